// Round 1
// baseline (4493.961 us; speedup 1.0000x reference)
//
#include <hip/hip_runtime.h>
#include <math.h>

#define BATCH 128
#define NF 128
#define NP 256

// ---------------- fused conv3x3(SAME) + ReLU + maxpool2 ----------------
// block = 256 threads = 16x16 pooled tile for one (b, co).
// Input staged in LDS in channel chunks of CC; each thread computes the
// 2x2 conv pixels feeding one pooled output.
template<int CIN, int CC>
__global__ void __launch_bounds__(256) conv_relu_pool(
    const float* __restrict__ in, const float* __restrict__ w,
    const float* __restrict__ bias, float* __restrict__ out,
    int Hin, int Win, int Cout, int tilesX)
{
    const int Hp = Hin >> 1, Wp = Win >> 1;
    const int tile = blockIdx.x;
    const int co   = blockIdx.y;
    const int b    = blockIdx.z;
    const int tyx  = tile / tilesX, txx = tile - tyx * tilesX;
    const int py0  = tyx * 16, px0 = txx * 16;      // pooled-tile origin
    const int tid  = threadIdx.x;
    const int tx   = tid & 15, ty = tid >> 4;

    __shared__ float smem[CC][34 * 34];

    const int y0 = py0 * 2 - 1;   // input row mapped to LDS iy=0
    const int x0 = px0 * 2 - 1;

    float acc[4] = {0.f, 0.f, 0.f, 0.f};  // 2x2 conv outputs (sy,sx)

    for (int c0 = 0; c0 < CIN; c0 += CC) {
        // ---- stage input chunk into LDS (zero-fill SAME padding) ----
        for (int idx = tid; idx < CC * 34 * 34; idx += 256) {
            int cc  = idx / (34 * 34);
            int rem = idx - cc * (34 * 34);
            int iy  = rem / 34, ix = rem - iy * 34;
            int gy = y0 + iy, gx = x0 + ix;
            float v = 0.f;
            if (gy >= 0 && gy < Hin && gx >= 0 && gx < Win)
                v = in[(((size_t)b * CIN + (c0 + cc)) * Hin + gy) * Win + gx];
            smem[cc][rem] = v;
        }
        __syncthreads();

        #pragma unroll
        for (int cc = 0; cc < CC; ++cc) {
            const float* wp = &w[(size_t)(co * CIN + c0 + cc) * 9];
            const float w00 = wp[0], w01 = wp[1], w02 = wp[2];
            const float w10 = wp[3], w11 = wp[4], w12 = wp[5];
            const float w20 = wp[6], w21 = wp[7], w22 = wp[8];

            // 4x4 input region: rows 2*ty..+3, cols 2*tx..+3 (8B aligned)
            float r[4][4];
            #pragma unroll
            for (int d = 0; d < 4; ++d) {
                const float2 a0 = *(const float2*)&smem[cc][(2 * ty + d) * 34 + 2 * tx];
                const float2 a1 = *(const float2*)&smem[cc][(2 * ty + d) * 34 + 2 * tx + 2];
                r[d][0] = a0.x; r[d][1] = a0.y; r[d][2] = a1.x; r[d][3] = a1.y;
            }
            #pragma unroll
            for (int sy = 0; sy < 2; ++sy)
                #pragma unroll
                for (int sx = 0; sx < 2; ++sx) {
                    float s = acc[sy * 2 + sx];
                    s += r[sy + 0][sx + 0] * w00 + r[sy + 0][sx + 1] * w01 + r[sy + 0][sx + 2] * w02;
                    s += r[sy + 1][sx + 0] * w10 + r[sy + 1][sx + 1] * w11 + r[sy + 1][sx + 2] * w12;
                    s += r[sy + 2][sx + 0] * w20 + r[sy + 2][sx + 1] * w21 + r[sy + 2][sx + 2] * w22;
                    acc[sy * 2 + sx] = s;
                }
        }
        __syncthreads();
    }

    // bias + ReLU commute with max: relu(max(acc)+b)
    const float bi = bias[co];
    float m = fmaxf(fmaxf(acc[0], acc[1]), fmaxf(acc[2], acc[3]));
    m = fmaxf(m + bi, 0.f);

    const int py = py0 + ty, px = px0 + tx;
    out[(((size_t)b * Cout + co) * Hp + py) * Wp + px] = m;
}

// ---------------- attention gate: sigmoid(feat[b,f,:]·Wa[f,:] + ba[f]) ----------------
__global__ void __launch_bounds__(256) attention_k(
    const float* __restrict__ feat, const float* __restrict__ Wa,
    const float* __restrict__ ba, float* __restrict__ att)
{
    const int wid  = blockIdx.x * 4 + (threadIdx.x >> 6);
    const int lane = threadIdx.x & 63;
    const int b = wid >> 7, f = wid & 127;

    const float4 a = ((const float4*)&feat[((size_t)b * NF + f) * NP])[lane];
    const float4 wv = ((const float4*)&Wa[(size_t)f * NP])[lane];
    float s = a.x * wv.x + a.y * wv.y + a.z * wv.z + a.w * wv.w;
    #pragma unroll
    for (int off = 32; off; off >>= 1) s += __shfl_down(s, off);
    if (lane == 0) att[b * NF + f] = 1.f / (1.f + expf(-(s + ba[f])));
}

// ---------------- per-expert gated MLP: 256 -> 256 -> 128 -> 32 ----------------
// block = (expert f, 32-row chunk). X and h1/h2 staged in LDS (padded rows).
__global__ void __launch_bounds__(256) experts_k(
    const float* __restrict__ feat, const float* __restrict__ att,
    const float* __restrict__ ew1, const float* __restrict__ eb1,
    const float* __restrict__ ew2, const float* __restrict__ eb2,
    const float* __restrict__ ew3, const float* __restrict__ eb3,
    float* __restrict__ z)   // z[B][4096], outer ReLU applied
{
    const int f  = blockIdx.x;
    const int r0 = blockIdx.y * 32;
    const int tid = threadIdx.x;

    __shared__ float xs [32][260];
    __shared__ float h1s[32][260];
    __shared__ float h2s[32][132];

    // stage gated input rows
    for (int idx = tid; idx < 32 * 256; idx += 256) {
        int r = idx >> 8, p = idx & 255;
        xs[r][p] = feat[((size_t)(r0 + r) * NF + f) * NP + p] * att[(r0 + r) * NF + f];
    }
    __syncthreads();

    // ---- layer 1: [32,256] @ [256,256], ReLU ----
    {
        const float* W1 = &ew1[(size_t)f * 256 * 256];
        const int c0  = (tid & 63) * 4;
        const int rr0 = (tid >> 6) * 8;
        float a[8][4] = {};
        for (int p = 0; p < 256; p += 4) {
            const float4 w0 = *(const float4*)&W1[(size_t)(p + 0) * 256 + c0];
            const float4 w1 = *(const float4*)&W1[(size_t)(p + 1) * 256 + c0];
            const float4 w2 = *(const float4*)&W1[(size_t)(p + 2) * 256 + c0];
            const float4 w3 = *(const float4*)&W1[(size_t)(p + 3) * 256 + c0];
            #pragma unroll
            for (int r = 0; r < 8; ++r) {
                const float4 xv = *(const float4*)&xs[rr0 + r][p];
                a[r][0] += xv.x * w0.x + xv.y * w1.x + xv.z * w2.x + xv.w * w3.x;
                a[r][1] += xv.x * w0.y + xv.y * w1.y + xv.z * w2.y + xv.w * w3.y;
                a[r][2] += xv.x * w0.z + xv.y * w1.z + xv.z * w2.z + xv.w * w3.z;
                a[r][3] += xv.x * w0.w + xv.y * w1.w + xv.z * w2.w + xv.w * w3.w;
            }
        }
        const float4 bv = *(const float4*)&eb1[(size_t)f * 256 + c0];
        #pragma unroll
        for (int r = 0; r < 8; ++r) {
            h1s[rr0 + r][c0 + 0] = fmaxf(a[r][0] + bv.x, 0.f);
            h1s[rr0 + r][c0 + 1] = fmaxf(a[r][1] + bv.y, 0.f);
            h1s[rr0 + r][c0 + 2] = fmaxf(a[r][2] + bv.z, 0.f);
            h1s[rr0 + r][c0 + 3] = fmaxf(a[r][3] + bv.w, 0.f);
        }
    }
    __syncthreads();

    // ---- layer 2: [32,256] @ [256,128], ReLU ----
    {
        const float* W2 = &ew2[(size_t)f * 256 * 128];
        const int c0  = (tid & 31) * 4;
        const int rr0 = (tid >> 5) * 4;
        float a[4][4] = {};
        for (int p = 0; p < 256; p += 4) {
            const float4 w0 = *(const float4*)&W2[(size_t)(p + 0) * 128 + c0];
            const float4 w1 = *(const float4*)&W2[(size_t)(p + 1) * 128 + c0];
            const float4 w2 = *(const float4*)&W2[(size_t)(p + 2) * 128 + c0];
            const float4 w3 = *(const float4*)&W2[(size_t)(p + 3) * 128 + c0];
            #pragma unroll
            for (int r = 0; r < 4; ++r) {
                const float4 xv = *(const float4*)&h1s[rr0 + r][p];
                a[r][0] += xv.x * w0.x + xv.y * w1.x + xv.z * w2.x + xv.w * w3.x;
                a[r][1] += xv.x * w0.y + xv.y * w1.y + xv.z * w2.y + xv.w * w3.y;
                a[r][2] += xv.x * w0.z + xv.y * w1.z + xv.z * w2.z + xv.w * w3.z;
                a[r][3] += xv.x * w0.w + xv.y * w1.w + xv.z * w2.w + xv.w * w3.w;
            }
        }
        const float4 bv = *(const float4*)&eb2[(size_t)f * 128 + c0];
        #pragma unroll
        for (int r = 0; r < 4; ++r) {
            h2s[rr0 + r][c0 + 0] = fmaxf(a[r][0] + bv.x, 0.f);
            h2s[rr0 + r][c0 + 1] = fmaxf(a[r][1] + bv.y, 0.f);
            h2s[rr0 + r][c0 + 2] = fmaxf(a[r][2] + bv.z, 0.f);
            h2s[rr0 + r][c0 + 3] = fmaxf(a[r][3] + bv.w, 0.f);
        }
    }
    __syncthreads();

    // ---- layer 3: [32,128] @ [128,32]  (+ outer ReLU, direct store) ----
    {
        const float* W3 = &ew3[(size_t)f * 128 * 32];
        const int c   = tid & 31;
        const int rr0 = (tid >> 5) * 4;
        float a[4] = {};
        for (int p = 0; p < 128; ++p) {
            const float wv = W3[(size_t)p * 32 + c];
            #pragma unroll
            for (int r = 0; r < 4; ++r) a[r] += h2s[rr0 + r][p] * wv;
        }
        const float b3 = eb3[(size_t)f * 32 + c];
        #pragma unroll
        for (int r = 0; r < 4; ++r)
            z[(size_t)(r0 + rr0 + r) * 4096 + f * 32 + c] = fmaxf(a[r] + b3, 0.f);
    }
}

// ---------------- final dense: [B,4096] @ [4096,53] + fb ----------------
__global__ void __launch_bounds__(256) final_k(
    const float* __restrict__ z, const float* __restrict__ fw,
    const float* __restrict__ fb, float* __restrict__ out)
{
    const int b = blockIdx.x;
    __shared__ float zs[4096];
    for (int i = threadIdx.x; i < 4096; i += 256) zs[i] = z[(size_t)b * 4096 + i];
    __syncthreads();

    const int wv = threadIdx.x >> 6, lane = threadIdx.x & 63;
    for (int o = wv; o < 53; o += 4) {
        float s = 0.f;
        for (int k = lane; k < 4096; k += 64) s += zs[k] * fw[(size_t)k * 53 + o];
        #pragma unroll
        for (int off = 32; off; off >>= 1) s += __shfl_down(s, off);
        if (lane == 0) out[b * 53 + o] = s + fb[o];
    }
}

extern "C" void kernel_launch(void* const* d_in, const int* in_sizes, int n_in,
                              void* d_out, int out_size, void* d_ws, size_t ws_size,
                              hipStream_t stream)
{
    const float* x   = (const float*)d_in[0];
    const float* cw1 = (const float*)d_in[1];
    const float* cb1 = (const float*)d_in[2];
    const float* cw2 = (const float*)d_in[3];
    const float* cb2 = (const float*)d_in[4];
    const float* cw3 = (const float*)d_in[5];
    const float* cb3 = (const float*)d_in[6];
    const float* Wa  = (const float*)d_in[7];
    const float* ba  = (const float*)d_in[8];
    const float* ew1 = (const float*)d_in[9];
    const float* eb1 = (const float*)d_in[10];
    const float* ew2 = (const float*)d_in[11];
    const float* eb2 = (const float*)d_in[12];
    const float* ew3 = (const float*)d_in[13];
    const float* eb3 = (const float*)d_in[14];
    const float* fw  = (const float*)d_in[15];
    const float* fb  = (const float*)d_in[16];

    float* ws   = (float*)d_ws;
    float* p1   = ws;                    // [128,32,64,64]  = 16777216 f
    float* p2   = p1 + 16777216;         // [128,64,32,32]  =  8388608 f
    float* feat = p2 + 8388608;          // [128,128,16,16] =  4194304 f
    float* att  = feat + 4194304;        // [128,128]       =    16384 f
    float* z    = ws;                    // [128,4096] reuses p1 region

    conv_relu_pool<3, 3><<<dim3(16, 32, 128), 256, 0, stream>>>(x,  cw1, cb1, p1,   128, 128, 32,  4);
    conv_relu_pool<32, 8><<<dim3(4, 64, 128), 256, 0, stream>>>(p1, cw2, cb2, p2,   64,  64,  64,  2);
    conv_relu_pool<64, 8><<<dim3(1, 128, 128), 256, 0, stream>>>(p2, cw3, cb3, feat, 32,  32,  128, 1);
    attention_k<<<4096, 256, 0, stream>>>(feat, Wa, ba, att);
    experts_k<<<dim3(128, 4), 256, 0, stream>>>(feat, att, ew1, eb1, ew2, eb2, ew3, eb3, z);
    final_k<<<128, 256, 0, stream>>>(z, fw, fb, (float*)d_out);
}

// Round 2
// 3393.981 us; speedup vs baseline: 1.3241x; 1.3241x over previous
//
#include <hip/hip_runtime.h>
#include <math.h>

#define BATCH 128
#define NF 128
#define NP 256

// ---------------- fused conv3x3(SAME) + ReLU + maxpool2 ----------------
// block = 256 threads = 16x16 pooled tile for one (b, co-group of COPB).
// Input staged in LDS in channel chunks of CC; each thread computes the
// 2x2 conv pixels feeding one pooled output, for COPB output channels.
// Weights are block-uniform -> scalar loads (free pipe).
template<int CIN, int CC, int COPB>
__global__ void __launch_bounds__(256) conv_relu_pool(
    const float* __restrict__ in, const float* __restrict__ w,
    const float* __restrict__ bias, float* __restrict__ out,
    int Hin, int Win, int Cout, int tilesX)
{
    const int Hp = Hin >> 1, Wp = Win >> 1;
    const int tile = blockIdx.x;
    const int co0  = blockIdx.y * COPB;
    const int b    = blockIdx.z;
    const int tyx  = tile / tilesX, txx = tile - tyx * tilesX;
    const int py0  = tyx * 16, px0 = txx * 16;      // pooled-tile origin
    const int tid  = threadIdx.x;
    const int tx   = tid & 15, ty = tid >> 4;

    __shared__ float smem[CC][34 * 34];

    const int y0 = py0 * 2 - 1;   // input row mapped to LDS iy=0
    const int x0 = px0 * 2 - 1;

    float acc[COPB][4];
    #pragma unroll
    for (int u = 0; u < COPB; ++u)
        #pragma unroll
        for (int q = 0; q < 4; ++q) acc[u][q] = 0.f;

    for (int c0 = 0; c0 < CIN; c0 += CC) {
        // ---- stage input chunk into LDS (zero-fill SAME padding) ----
        for (int idx = tid; idx < CC * 34 * 34; idx += 256) {
            int cc  = idx / (34 * 34);
            int rem = idx - cc * (34 * 34);
            int iy  = rem / 34, ix = rem - iy * 34;
            int gy = y0 + iy, gx = x0 + ix;
            float v = 0.f;
            if (gy >= 0 && gy < Hin && gx >= 0 && gx < Win)
                v = in[(((size_t)b * CIN + (c0 + cc)) * Hin + gy) * Win + gx];
            smem[cc][rem] = v;
        }
        __syncthreads();

        #pragma unroll
        for (int cc = 0; cc < CC; ++cc) {
            // 4x4 input region: rows 2*ty..+3, cols 2*tx..+3 (8B aligned)
            float r[4][4];
            #pragma unroll
            for (int d = 0; d < 4; ++d) {
                const float2 a0 = *(const float2*)&smem[cc][(2 * ty + d) * 34 + 2 * tx];
                const float2 a1 = *(const float2*)&smem[cc][(2 * ty + d) * 34 + 2 * tx + 2];
                r[d][0] = a0.x; r[d][1] = a0.y; r[d][2] = a1.x; r[d][3] = a1.y;
            }
            #pragma unroll
            for (int u = 0; u < COPB; ++u) {
                const float* wp = &w[(size_t)((co0 + u) * CIN + c0 + cc) * 9];
                const float w00 = wp[0], w01 = wp[1], w02 = wp[2];
                const float w10 = wp[3], w11 = wp[4], w12 = wp[5];
                const float w20 = wp[6], w21 = wp[7], w22 = wp[8];
                #pragma unroll
                for (int sy = 0; sy < 2; ++sy)
                    #pragma unroll
                    for (int sx = 0; sx < 2; ++sx) {
                        float s = acc[u][sy * 2 + sx];
                        s += r[sy + 0][sx + 0] * w00 + r[sy + 0][sx + 1] * w01 + r[sy + 0][sx + 2] * w02;
                        s += r[sy + 1][sx + 0] * w10 + r[sy + 1][sx + 1] * w11 + r[sy + 1][sx + 2] * w12;
                        s += r[sy + 2][sx + 0] * w20 + r[sy + 2][sx + 1] * w21 + r[sy + 2][sx + 2] * w22;
                        acc[u][sy * 2 + sx] = s;
                    }
            }
        }
        __syncthreads();
    }

    // bias + ReLU commute with max: relu(max(acc)+b)
    const int py = py0 + ty, px = px0 + tx;
    #pragma unroll
    for (int u = 0; u < COPB; ++u) {
        const float bi = bias[co0 + u];
        float m = fmaxf(fmaxf(acc[u][0], acc[u][1]), fmaxf(acc[u][2], acc[u][3]));
        m = fmaxf(m + bi, 0.f);
        out[(((size_t)b * Cout + co0 + u) * Hp + py) * Wp + px] = m;
    }
}

// ---------------- attention gate: sigmoid(feat[b,f,:]·Wa[f,:] + ba[f]) ----------------
__global__ void __launch_bounds__(256) attention_k(
    const float* __restrict__ feat, const float* __restrict__ Wa,
    const float* __restrict__ ba, float* __restrict__ att)
{
    const int wid  = blockIdx.x * 4 + (threadIdx.x >> 6);
    const int lane = threadIdx.x & 63;
    const int b = wid >> 7, f = wid & 127;

    const float4 a = ((const float4*)&feat[((size_t)b * NF + f) * NP])[lane];
    const float4 wv = ((const float4*)&Wa[(size_t)f * NP])[lane];
    float s = a.x * wv.x + a.y * wv.y + a.z * wv.z + a.w * wv.w;
    #pragma unroll
    for (int off = 32; off; off >>= 1) s += __shfl_down(s, off);
    if (lane == 0) att[b * NF + f] = 1.f / (1.f + expf(-(s + ba[f])));
}

// ---------------- per-expert gated MLP: 256 -> 256 -> 128 -> 32 ----------------
// block = (expert f, 32-row chunk). X and h1/h2 staged in LDS (padded rows).
__global__ void __launch_bounds__(256) experts_k(
    const float* __restrict__ feat, const float* __restrict__ att,
    const float* __restrict__ ew1, const float* __restrict__ eb1,
    const float* __restrict__ ew2, const float* __restrict__ eb2,
    const float* __restrict__ ew3, const float* __restrict__ eb3,
    float* __restrict__ z)   // z[B][4096], outer ReLU applied
{
    const int f  = blockIdx.x;
    const int r0 = blockIdx.y * 32;
    const int tid = threadIdx.x;

    __shared__ float xs [32][260];
    __shared__ float h1s[32][260];
    __shared__ float h2s[32][132];

    // stage gated input rows
    for (int idx = tid; idx < 32 * 256; idx += 256) {
        int r = idx >> 8, p = idx & 255;
        xs[r][p] = feat[((size_t)(r0 + r) * NF + f) * NP + p] * att[(r0 + r) * NF + f];
    }
    __syncthreads();

    // ---- layer 1: [32,256] @ [256,256], ReLU ----
    {
        const float* W1 = &ew1[(size_t)f * 256 * 256];
        const int c0  = (tid & 63) * 4;
        const int rr0 = (tid >> 6) * 8;
        float a[8][4] = {};
        for (int p = 0; p < 256; p += 4) {
            const float4 w0 = *(const float4*)&W1[(size_t)(p + 0) * 256 + c0];
            const float4 w1 = *(const float4*)&W1[(size_t)(p + 1) * 256 + c0];
            const float4 w2 = *(const float4*)&W1[(size_t)(p + 2) * 256 + c0];
            const float4 w3 = *(const float4*)&W1[(size_t)(p + 3) * 256 + c0];
            #pragma unroll
            for (int r = 0; r < 8; ++r) {
                const float4 xv = *(const float4*)&xs[rr0 + r][p];
                a[r][0] += xv.x * w0.x + xv.y * w1.x + xv.z * w2.x + xv.w * w3.x;
                a[r][1] += xv.x * w0.y + xv.y * w1.y + xv.z * w2.y + xv.w * w3.y;
                a[r][2] += xv.x * w0.z + xv.y * w1.z + xv.z * w2.z + xv.w * w3.z;
                a[r][3] += xv.x * w0.w + xv.y * w1.w + xv.z * w2.w + xv.w * w3.w;
            }
        }
        const float4 bv = *(const float4*)&eb1[(size_t)f * 256 + c0];
        #pragma unroll
        for (int r = 0; r < 8; ++r) {
            h1s[rr0 + r][c0 + 0] = fmaxf(a[r][0] + bv.x, 0.f);
            h1s[rr0 + r][c0 + 1] = fmaxf(a[r][1] + bv.y, 0.f);
            h1s[rr0 + r][c0 + 2] = fmaxf(a[r][2] + bv.z, 0.f);
            h1s[rr0 + r][c0 + 3] = fmaxf(a[r][3] + bv.w, 0.f);
        }
    }
    __syncthreads();

    // ---- layer 2: [32,256] @ [256,128], ReLU ----
    {
        const float* W2 = &ew2[(size_t)f * 256 * 128];
        const int c0  = (tid & 31) * 4;
        const int rr0 = (tid >> 5) * 4;
        float a[4][4] = {};
        for (int p = 0; p < 256; p += 4) {
            const float4 w0 = *(const float4*)&W2[(size_t)(p + 0) * 128 + c0];
            const float4 w1 = *(const float4*)&W2[(size_t)(p + 1) * 128 + c0];
            const float4 w2 = *(const float4*)&W2[(size_t)(p + 2) * 128 + c0];
            const float4 w3 = *(const float4*)&W2[(size_t)(p + 3) * 128 + c0];
            #pragma unroll
            for (int r = 0; r < 4; ++r) {
                const float4 xv = *(const float4*)&h1s[rr0 + r][p];
                a[r][0] += xv.x * w0.x + xv.y * w1.x + xv.z * w2.x + xv.w * w3.x;
                a[r][1] += xv.x * w0.y + xv.y * w1.y + xv.z * w2.y + xv.w * w3.y;
                a[r][2] += xv.x * w0.z + xv.y * w1.z + xv.z * w2.z + xv.w * w3.z;
                a[r][3] += xv.x * w0.w + xv.y * w1.w + xv.z * w2.w + xv.w * w3.w;
            }
        }
        const float4 bv = *(const float4*)&eb2[(size_t)f * 128 + c0];
        #pragma unroll
        for (int r = 0; r < 4; ++r) {
            h2s[rr0 + r][c0 + 0] = fmaxf(a[r][0] + bv.x, 0.f);
            h2s[rr0 + r][c0 + 1] = fmaxf(a[r][1] + bv.y, 0.f);
            h2s[rr0 + r][c0 + 2] = fmaxf(a[r][2] + bv.z, 0.f);
            h2s[rr0 + r][c0 + 3] = fmaxf(a[r][3] + bv.w, 0.f);
        }
    }
    __syncthreads();

    // ---- layer 3: [32,128] @ [128,32]  (+ outer ReLU, direct store) ----
    {
        const float* W3 = &ew3[(size_t)f * 128 * 32];
        const int c   = tid & 31;
        const int rr0 = (tid >> 5) * 4;
        float a[4] = {};
        for (int p = 0; p < 128; ++p) {
            const float wv = W3[(size_t)p * 32 + c];
            #pragma unroll
            for (int r = 0; r < 4; ++r) a[r] += h2s[rr0 + r][p] * wv;
        }
        const float b3 = eb3[(size_t)f * 32 + c];
        #pragma unroll
        for (int r = 0; r < 4; ++r)
            z[(size_t)(r0 + rr0 + r) * 4096 + f * 32 + c] = fmaxf(a[r] + b3, 0.f);
    }
}

// ---------------- final dense: [B,4096] @ [4096,53] + fb ----------------
__global__ void __launch_bounds__(256) final_k(
    const float* __restrict__ z, const float* __restrict__ fw,
    const float* __restrict__ fb, float* __restrict__ out)
{
    const int b = blockIdx.x;
    __shared__ float zs[4096];
    for (int i = threadIdx.x; i < 4096; i += 256) zs[i] = z[(size_t)b * 4096 + i];
    __syncthreads();

    const int wv = threadIdx.x >> 6, lane = threadIdx.x & 63;
    for (int o = wv; o < 53; o += 4) {
        float s = 0.f;
        for (int k = lane; k < 4096; k += 64) s += zs[k] * fw[(size_t)k * 53 + o];
        #pragma unroll
        for (int off = 32; off; off >>= 1) s += __shfl_down(s, off);
        if (lane == 0) out[b * 53 + o] = s + fb[o];
    }
}

extern "C" void kernel_launch(void* const* d_in, const int* in_sizes, int n_in,
                              void* d_out, int out_size, void* d_ws, size_t ws_size,
                              hipStream_t stream)
{
    const float* x   = (const float*)d_in[0];
    const float* cw1 = (const float*)d_in[1];
    const float* cb1 = (const float*)d_in[2];
    const float* cw2 = (const float*)d_in[3];
    const float* cb2 = (const float*)d_in[4];
    const float* cw3 = (const float*)d_in[5];
    const float* cb3 = (const float*)d_in[6];
    const float* Wa  = (const float*)d_in[7];
    const float* ba  = (const float*)d_in[8];
    const float* ew1 = (const float*)d_in[9];
    const float* eb1 = (const float*)d_in[10];
    const float* ew2 = (const float*)d_in[11];
    const float* eb2 = (const float*)d_in[12];
    const float* ew3 = (const float*)d_in[13];
    const float* eb3 = (const float*)d_in[14];
    const float* fw  = (const float*)d_in[15];
    const float* fb  = (const float*)d_in[16];

    float* ws   = (float*)d_ws;
    float* p1   = ws;                    // [128,32,64,64]  = 16777216 f
    float* p2   = p1 + 16777216;         // [128,64,32,32]  =  8388608 f
    float* feat = p2 + 8388608;          // [128,128,16,16] =  4194304 f
    float* att  = feat + 4194304;        // [128,128]       =    16384 f
    float* z    = ws;                    // [128,4096] reuses p1 region

    // conv1: 3->32, 128x128 in, tiles 4x4, co-groups 32/8=4
    conv_relu_pool<3, 3, 8><<<dim3(16, 4, 128), 256, 0, stream>>>(x,  cw1, cb1, p1,   128, 128, 32,  4);
    // conv2: 32->64, 64x64 in, tiles 2x2, co-groups 64/8=8
    conv_relu_pool<32, 8, 8><<<dim3(4, 8, 128), 256, 0, stream>>>(p1, cw2, cb2, p2,   64,  64,  64,  2);
    // conv3: 64->128, 32x32 in, 1 tile, co-groups 128/16=8
    conv_relu_pool<64, 8, 16><<<dim3(1, 8, 128), 256, 0, stream>>>(p2, cw3, cb3, feat, 32,  32,  128, 1);
    attention_k<<<4096, 256, 0, stream>>>(feat, Wa, ba, att);
    experts_k<<<dim3(128, 4), 256, 0, stream>>>(feat, att, ew1, eb1, ew2, eb2, ew3, eb3, z);
    final_k<<<128, 256, 0, stream>>>(z, fw, fb, (float*)d_out);
}

// Round 3
// 469.225 us; speedup vs baseline: 9.5774x; 7.2332x over previous
//
#include <hip/hip_runtime.h>
#include <hip/hip_bf16.h>
#include <math.h>

#define NF 128
#define NP 256

typedef __attribute__((ext_vector_type(8))) short bf16x8;
typedef __attribute__((ext_vector_type(4))) float f32x4;

// ---------------- weight pre-pack: [cout][cin][3][3] f32 -> [o][cout][cin] bf16 ----------------
__global__ void __launch_bounds__(256) wpack_k(const float* __restrict__ w,
                                               __hip_bfloat16* __restrict__ wp,
                                               int COUT, int CIN)
{
    int i = blockIdx.x * 256 + threadIdx.x;
    int total = 9 * COUT * CIN;
    if (i >= total) return;
    int o  = i / (COUT * CIN);
    int r  = i - o * (COUT * CIN);
    int co = r / CIN, ci = r - co * CIN;
    wp[i] = __float2bfloat16(w[(size_t)(co * CIN + ci) * 9 + o]);
}

// ---------------- conv1: 3->32, fp32 VALU, writes bf16 channel-last [b][64][64][32] ----------------
__global__ void __launch_bounds__(256) conv1_k(
    const float* __restrict__ x, const float* __restrict__ w,
    const float* __restrict__ bias, __hip_bfloat16* __restrict__ out)
{
    const int tile = blockIdx.x;
    const int co0  = blockIdx.y * 16;
    const int b    = blockIdx.z;
    const int tyx  = tile >> 2, txx = tile & 3;
    const int py0  = tyx * 16, px0 = txx * 16;
    const int tid  = threadIdx.x, tx = tid & 15, ty = tid >> 4;

    __shared__ float smem[3][34 * 34];
    const int y0 = py0 * 2 - 1, x0 = px0 * 2 - 1;
    for (int idx = tid; idx < 3 * 1156; idx += 256) {
        int cc = idx / 1156, rem = idx - cc * 1156;
        int iy = rem / 34, ix = rem - iy * 34;
        int gy = y0 + iy, gx = x0 + ix;
        float v = 0.f;
        if (gy >= 0 && gy < 128 && gx >= 0 && gx < 128)
            v = x[((size_t)(b * 3 + cc) * 128 + gy) * 128 + gx];
        smem[cc][rem] = v;
    }
    __syncthreads();

    float acc[16][4];
    #pragma unroll
    for (int u = 0; u < 16; ++u)
        #pragma unroll
        for (int qq = 0; qq < 4; ++qq) acc[u][qq] = 0.f;

    #pragma unroll
    for (int cc = 0; cc < 3; ++cc) {
        float r[4][4];
        #pragma unroll
        for (int d = 0; d < 4; ++d) {
            const float2 a0 = *(const float2*)&smem[cc][(2 * ty + d) * 34 + 2 * tx];
            const float2 a1 = *(const float2*)&smem[cc][(2 * ty + d) * 34 + 2 * tx + 2];
            r[d][0] = a0.x; r[d][1] = a0.y; r[d][2] = a1.x; r[d][3] = a1.y;
        }
        #pragma unroll
        for (int u = 0; u < 16; ++u) {
            const float* wp = &w[((size_t)(co0 + u) * 3 + cc) * 9];
            const float w00 = wp[0], w01 = wp[1], w02 = wp[2];
            const float w10 = wp[3], w11 = wp[4], w12 = wp[5];
            const float w20 = wp[6], w21 = wp[7], w22 = wp[8];
            #pragma unroll
            for (int sy = 0; sy < 2; ++sy)
                #pragma unroll
                for (int sx = 0; sx < 2; ++sx) {
                    float s = acc[u][sy * 2 + sx];
                    s += r[sy + 0][sx + 0] * w00 + r[sy + 0][sx + 1] * w01 + r[sy + 0][sx + 2] * w02;
                    s += r[sy + 1][sx + 0] * w10 + r[sy + 1][sx + 1] * w11 + r[sy + 1][sx + 2] * w12;
                    s += r[sy + 2][sx + 0] * w20 + r[sy + 2][sx + 1] * w21 + r[sy + 2][sx + 2] * w22;
                    acc[u][sy * 2 + sx] = s;
                }
        }
    }

    unsigned short hv[16];
    #pragma unroll
    for (int u = 0; u < 16; ++u) {
        float m = fmaxf(fmaxf(acc[u][0], acc[u][1]), fmaxf(acc[u][2], acc[u][3]));
        m = fmaxf(m + bias[co0 + u], 0.f);
        __hip_bfloat16 hb = __float2bfloat16(m);
        __builtin_memcpy(&hv[u], &hb, 2);
    }
    const int py = py0 + ty, px = px0 + tx;
    size_t obase = ((size_t)(b * 64 + py) * 64 + px) * 32 + co0;
    *(int4*)(out + obase)     = *(const int4*)&hv[0];
    *(int4*)(out + obase + 8) = *(const int4*)&hv[8];
}

// ---------------- MFMA conv3x3 + ReLU + maxpool2 (implicit GEMM, 9 shifted GEMMs) ----------------
// in: bf16 channel-last [b][W][W][CIN]. Block = 8 conv rows x W, 4 waves.
// Wave = 2 rows (M = 2*W pixels) x full COUT. K-step = (offset o, cin half h).
// OUTF=0: write bf16 ch-last pooled [b][W/2][W/2][COUT]; OUTF=1: fp32 [b][COUT][(W/2)^2] via LDS transpose.
template<int W, int CIN, int COUT, int SWZ, int OUTF>
__global__ void __launch_bounds__(256, 2) conv_mfma(
    const __hip_bfloat16* __restrict__ in,
    const __hip_bfloat16* __restrict__ wp,
    const float* __restrict__ bias,
    __hip_bfloat16* __restrict__ outb,
    float* __restrict__ outf)
{
    constexpr int XW  = W / 16;        // A frags per row
    constexpr int AF  = 2 * XW;        // A frags per wave (2 rows)
    constexpr int BF  = COUT / 16;     // B frags
    constexpr int CH  = CIN / 8;       // 16B chunks per pixel
    constexpr int KH  = CIN / 32;      // K half-steps per offset
    constexpr int PXW = W + 2;
    constexpr int UNITS  = 10 * PXW * CH;
    constexpr int STAGEB = UNITS * 16;
    constexpr int OUTLDS = OUTF ? (COUT * 68 * 4) : 0;
    constexpr int LDSB   = STAGEB > OUTLDS ? STAGEB : OUTLDS;

    __shared__ int4 ldsv[(LDSB + 15) / 16];
    char* ldsc = (char*)ldsv;

    const int rb  = blockIdx.x * 8;    // conv-row base
    const int b   = blockIdx.z;
    const int tid = threadIdx.x;

    // ---- stage input tile (rows rb-1..rb+8, x -1..W) ----
    for (int u = tid; u < UNITS; u += 256) {
        int ch = u % CH; int pl = u / CH;
        int xx = pl % PXW; int row = pl / PXW;
        int gy = rb + row - 1, gx = xx - 1;
        int4 v = make_int4(0, 0, 0, 0);
        if (gy >= 0 && gy < W && gx >= 0 && gx < W)
            v = *(const int4*)(in + ((size_t)(b * W + gy) * W + gx) * CIN + ch * 8);
        int slot = SWZ ? (pl * CH + (ch ^ (pl & 7))) : (pl * CH + ch);
        *(int4*)(ldsc + slot * 16) = v;
    }
    __syncthreads();

    const int w = tid >> 6, lane = tid & 63, p = lane & 15, q = lane >> 4;

    f32x4 acc[AF][BF];
    #pragma unroll
    for (int m = 0; m < AF; ++m)
        #pragma unroll
        for (int n = 0; n < BF; ++n) {
            acc[m][n][0] = 0.f; acc[m][n][1] = 0.f;
            acc[m][n][2] = 0.f; acc[m][n][3] = 0.f;
        }

    float bv[BF];
    #pragma unroll
    for (int n = 0; n < BF; ++n) bv[n] = bias[n * 16 + p];

    #pragma unroll 1
    for (int o = 0; o < 9; ++o) {
        const int ky = o / 3, kx = o - 3 * (o / 3);
        #pragma unroll
        for (int h = 0; h < KH; ++h) {
            bf16x8 bfr[BF];
            #pragma unroll
            for (int n = 0; n < BF; ++n)
                bfr[n] = *(const bf16x8*)(wp + (size_t)(o * COUT + n * 16 + p) * CIN + h * 32 + q * 8);
            bf16x8 afr[AF];
            #pragma unroll
            for (int m = 0; m < AF; ++m) {
                const int mr = m / XW, mx = m % XW;
                const int pix = (2 * w + mr + ky) * PXW + mx * 16 + kx + p;
                const int ch = h * 4 + q;
                const int slot = SWZ ? (pix * CH + (ch ^ (pix & 7))) : (pix * CH + ch);
                afr[m] = *(const bf16x8*)(ldsc + slot * 16);
            }
            #pragma unroll
            for (int m = 0; m < AF; ++m)
                #pragma unroll
                for (int n = 0; n < BF; ++n)
                    acc[m][n] = __builtin_amdgcn_mfma_f32_16x16x32_bf16(afr[m], bfr[n], acc[m][n], 0, 0, 0);
        }
    }

    // ---- pool 2x2 + bias + ReLU + write ----
    // D mapping (verified): n = lane&15, pixel-x = (lane>>4)*4 + reg. Row pairs = frag pairs (m, m+XW),
    // x pairs = reg pairs (0,1),(2,3).
    const int prow = (rb >> 1) + w;
    if constexpr (OUTF == 0) {
        #pragma unroll
        for (int mx = 0; mx < XW; ++mx)
            #pragma unroll
            for (int n = 0; n < BF; ++n) {
                f32x4 lo = acc[mx][n], hi = acc[XW + mx][n];
                float v0 = fmaxf(fmaxf(fmaxf(lo[0], lo[1]), fmaxf(hi[0], hi[1])) + bv[n], 0.f);
                float v1 = fmaxf(fmaxf(fmaxf(lo[2], lo[3]), fmaxf(hi[2], hi[3])) + bv[n], 0.f);
                int px = mx * 8 + q * 2;
                size_t base = ((size_t)(b * (W / 2) + prow) * (W / 2) + px) * COUT + n * 16 + p;
                outb[base]        = __float2bfloat16(v0);
                outb[base + COUT] = __float2bfloat16(v1);
            }
    } else {
        __syncthreads();   // all waves done reading input LDS
        float* fl = (float*)ldsc;
        #pragma unroll
        for (int mx = 0; mx < XW; ++mx)
            #pragma unroll
            for (int n = 0; n < BF; ++n) {
                f32x4 lo = acc[mx][n], hi = acc[XW + mx][n];
                float v0 = fmaxf(fmaxf(fmaxf(lo[0], lo[1]), fmaxf(hi[0], hi[1])) + bv[n], 0.f);
                float v1 = fmaxf(fmaxf(fmaxf(lo[2], lo[3]), fmaxf(hi[2], hi[3])) + bv[n], 0.f);
                int px = mx * 8 + q * 2;
                fl[(n * 16 + p) * 68 + w * 16 + px]     = v0;
                fl[(n * 16 + p) * 68 + w * 16 + px + 1] = v1;
            }
        __syncthreads();
        // coalesced fp32: feat[b][c][(rb/2)*16 + j], j = 0..63
        for (int i = tid; i < COUT * 16; i += 256) {
            int c = i >> 4, j4 = i & 15;
            float4 vv = *(const float4*)&fl[c * 68 + j4 * 4];
            *(float4*)(outf + (size_t)(b * COUT + c) * 256 + (rb >> 1) * 16 + j4 * 4) = vv;
        }
    }
}

// ---------------- attention gate: sigmoid(feat[b,f,:]·Wa[f,:] + ba[f]) ----------------
__global__ void __launch_bounds__(256) attention_k(
    const float* __restrict__ feat, const float* __restrict__ Wa,
    const float* __restrict__ ba, float* __restrict__ att)
{
    const int wid  = blockIdx.x * 4 + (threadIdx.x >> 6);
    const int lane = threadIdx.x & 63;
    const int b = wid >> 7, f = wid & 127;

    const float4 a  = ((const float4*)&feat[((size_t)b * NF + f) * NP])[lane];
    const float4 wv = ((const float4*)&Wa[(size_t)f * NP])[lane];
    float s = a.x * wv.x + a.y * wv.y + a.z * wv.z + a.w * wv.w;
    #pragma unroll
    for (int off = 32; off; off >>= 1) s += __shfl_down(s, off);
    if (lane == 0) att[b * NF + f] = 1.f / (1.f + expf(-(s + ba[f])));
}

// ---------------- per-expert gated MLP: 256 -> 256 -> 128 -> 32 ----------------
__global__ void __launch_bounds__(256) experts_k(
    const float* __restrict__ feat, const float* __restrict__ att,
    const float* __restrict__ ew1, const float* __restrict__ eb1,
    const float* __restrict__ ew2, const float* __restrict__ eb2,
    const float* __restrict__ ew3, const float* __restrict__ eb3,
    float* __restrict__ z)
{
    const int f  = blockIdx.x;
    const int r0 = blockIdx.y * 32;
    const int tid = threadIdx.x;

    __shared__ float xs [32][260];
    __shared__ float h1s[32][260];
    __shared__ float h2s[32][132];

    for (int idx = tid; idx < 32 * 256; idx += 256) {
        int r = idx >> 8, pp = idx & 255;
        xs[r][pp] = feat[((size_t)(r0 + r) * NF + f) * NP + pp] * att[(r0 + r) * NF + f];
    }
    __syncthreads();

    {
        const float* W1 = &ew1[(size_t)f * 256 * 256];
        const int c0  = (tid & 63) * 4;
        const int rr0 = (tid >> 6) * 8;
        float a[8][4] = {};
        for (int pp = 0; pp < 256; pp += 4) {
            const float4 w0 = *(const float4*)&W1[(size_t)(pp + 0) * 256 + c0];
            const float4 w1 = *(const float4*)&W1[(size_t)(pp + 1) * 256 + c0];
            const float4 w2 = *(const float4*)&W1[(size_t)(pp + 2) * 256 + c0];
            const float4 w3 = *(const float4*)&W1[(size_t)(pp + 3) * 256 + c0];
            #pragma unroll
            for (int r = 0; r < 8; ++r) {
                const float4 xv = *(const float4*)&xs[rr0 + r][pp];
                a[r][0] += xv.x * w0.x + xv.y * w1.x + xv.z * w2.x + xv.w * w3.x;
                a[r][1] += xv.x * w0.y + xv.y * w1.y + xv.z * w2.y + xv.w * w3.y;
                a[r][2] += xv.x * w0.z + xv.y * w1.z + xv.z * w2.z + xv.w * w3.z;
                a[r][3] += xv.x * w0.w + xv.y * w1.w + xv.z * w2.w + xv.w * w3.w;
            }
        }
        const float4 bvv = *(const float4*)&eb1[(size_t)f * 256 + c0];
        #pragma unroll
        for (int r = 0; r < 8; ++r) {
            h1s[rr0 + r][c0 + 0] = fmaxf(a[r][0] + bvv.x, 0.f);
            h1s[rr0 + r][c0 + 1] = fmaxf(a[r][1] + bvv.y, 0.f);
            h1s[rr0 + r][c0 + 2] = fmaxf(a[r][2] + bvv.z, 0.f);
            h1s[rr0 + r][c0 + 3] = fmaxf(a[r][3] + bvv.w, 0.f);
        }
    }
    __syncthreads();

    {
        const float* W2 = &ew2[(size_t)f * 256 * 128];
        const int c0  = (tid & 31) * 4;
        const int rr0 = (tid >> 5) * 4;
        float a[4][4] = {};
        for (int pp = 0; pp < 256; pp += 4) {
            const float4 w0 = *(const float4*)&W2[(size_t)(pp + 0) * 128 + c0];
            const float4 w1 = *(const float4*)&W2[(size_t)(pp + 1) * 128 + c0];
            const float4 w2 = *(const float4*)&W2[(size_t)(pp + 2) * 128 + c0];
            const float4 w3 = *(const float4*)&W2[(size_t)(pp + 3) * 128 + c0];
            #pragma unroll
            for (int r = 0; r < 4; ++r) {
                const float4 xv = *(const float4*)&h1s[rr0 + r][pp];
                a[r][0] += xv.x * w0.x + xv.y * w1.x + xv.z * w2.x + xv.w * w3.x;
                a[r][1] += xv.x * w0.y + xv.y * w1.y + xv.z * w2.y + xv.w * w3.y;
                a[r][2] += xv.x * w0.z + xv.y * w1.z + xv.z * w2.z + xv.w * w3.z;
                a[r][3] += xv.x * w0.w + xv.y * w1.w + xv.z * w2.w + xv.w * w3.w;
            }
        }
        const float4 bvv = *(const float4*)&eb2[(size_t)f * 128 + c0];
        #pragma unroll
        for (int r = 0; r < 4; ++r) {
            h2s[rr0 + r][c0 + 0] = fmaxf(a[r][0] + bvv.x, 0.f);
            h2s[rr0 + r][c0 + 1] = fmaxf(a[r][1] + bvv.y, 0.f);
            h2s[rr0 + r][c0 + 2] = fmaxf(a[r][2] + bvv.z, 0.f);
            h2s[rr0 + r][c0 + 3] = fmaxf(a[r][3] + bvv.w, 0.f);
        }
    }
    __syncthreads();

    {
        const float* W3 = &ew3[(size_t)f * 128 * 32];
        const int c   = tid & 31;
        const int rr0 = (tid >> 5) * 4;
        float a[4] = {};
        for (int pp = 0; pp < 128; ++pp) {
            const float wv = W3[(size_t)pp * 32 + c];
            #pragma unroll
            for (int r = 0; r < 4; ++r) a[r] += h2s[rr0 + r][pp] * wv;
        }
        const float b3 = eb3[(size_t)f * 32 + c];
        #pragma unroll
        for (int r = 0; r < 4; ++r)
            z[(size_t)(r0 + rr0 + r) * 4096 + f * 32 + c] = fmaxf(a[r] + b3, 0.f);
    }
}

// ---------------- final dense: [B,4096] @ [4096,53] + fb ----------------
__global__ void __launch_bounds__(256) final_k(
    const float* __restrict__ z, const float* __restrict__ fw,
    const float* __restrict__ fb, float* __restrict__ out)
{
    const int b = blockIdx.x;
    __shared__ float zs[4096];
    for (int i = threadIdx.x; i < 4096; i += 256) zs[i] = z[(size_t)b * 4096 + i];
    __syncthreads();

    const int wv = threadIdx.x >> 6, lane = threadIdx.x & 63;
    for (int o = wv; o < 53; o += 4) {
        float s = 0.f;
        for (int k = lane; k < 4096; k += 64) s += zs[k] * fw[(size_t)k * 53 + o];
        #pragma unroll
        for (int off = 32; off; off >>= 1) s += __shfl_down(s, off);
        if (lane == 0) out[b * 53 + o] = s + fb[o];
    }
}

extern "C" void kernel_launch(void* const* d_in, const int* in_sizes, int n_in,
                              void* d_out, int out_size, void* d_ws, size_t ws_size,
                              hipStream_t stream)
{
    const float* x   = (const float*)d_in[0];
    const float* cw1 = (const float*)d_in[1];
    const float* cb1 = (const float*)d_in[2];
    const float* cw2 = (const float*)d_in[3];
    const float* cb2 = (const float*)d_in[4];
    const float* cw3 = (const float*)d_in[5];
    const float* cb3 = (const float*)d_in[6];
    const float* Wa  = (const float*)d_in[7];
    const float* ba  = (const float*)d_in[8];
    const float* ew1 = (const float*)d_in[9];
    const float* eb1 = (const float*)d_in[10];
    const float* ew2 = (const float*)d_in[11];
    const float* eb2 = (const float*)d_in[12];
    const float* ew3 = (const float*)d_in[13];
    const float* eb3 = (const float*)d_in[14];
    const float* fw  = (const float*)d_in[15];
    const float* fb  = (const float*)d_in[16];

    float* ws = (float*)d_ws;
    __hip_bfloat16* p1b = (__hip_bfloat16*)ws;                       // [128][64][64][32] bf16 = 8,388,608 f
    __hip_bfloat16* p2b = (__hip_bfloat16*)(ws + 8388608);           // [128][32][32][64] bf16 = 4,194,304 f
    float* feat = ws + 8388608 + 4194304;                            // [128][128][256] f32 = 4,194,304 f
    float* att  = feat + 4194304;                                    // [128][128]
    __hip_bfloat16* wp2 = (__hip_bfloat16*)(att + 16384);            // [9][64][32]  bf16 = 9,216 f
    __hip_bfloat16* wp3 = (__hip_bfloat16*)(att + 16384 + 9216);     // [9][128][64] bf16 = 36,864 f
    float* z = ws;                                                   // [128][4096], reuses p1b (dead after conv2)

    wpack_k<<<72, 256, 0, stream>>>(cw2, wp2, 64, 32);
    wpack_k<<<288, 256, 0, stream>>>(cw3, wp3, 128, 64);
    conv1_k<<<dim3(16, 2, 128), 256, 0, stream>>>(x, cw1, cb1, p1b);
    conv_mfma<64, 32, 64, 0, 0><<<dim3(8, 1, 128), 256, 0, stream>>>(p1b, wp2, cb2, p2b, nullptr);
    conv_mfma<32, 64, 128, 1, 1><<<dim3(4, 1, 128), 256, 0, stream>>>(p2b, wp3, cb3, nullptr, feat);
    attention_k<<<4096, 256, 0, stream>>>(feat, Wa, ba, att);
    experts_k<<<dim3(128, 4), 256, 0, stream>>>(feat, att, ew1, eb1, ew2, eb2, ew3, eb3, z);
    final_k<<<128, 256, 0, stream>>>(z, fw, fb, (float*)d_out);
}

// Round 9
// 228.438 us; speedup vs baseline: 19.6726x; 2.0541x over previous
//
#include <hip/hip_runtime.h>
#include <hip/hip_bf16.h>
#include <math.h>

#define NF 128
#define NP 256

typedef __attribute__((ext_vector_type(8))) short bf16x8;
typedef __attribute__((ext_vector_type(4))) float f32x4;

// ---------------- conv weight pre-pack: [cout][cin][3][3] f32 -> [o][cout][cin] bf16 ----------------
__global__ void __launch_bounds__(256) wpack_k(const float* __restrict__ w,
                                               __hip_bfloat16* __restrict__ wp,
                                               int COUT, int CIN)
{
    int i = blockIdx.x * 256 + threadIdx.x;
    int total = 9 * COUT * CIN;
    if (i >= total) return;
    int o  = i / (COUT * CIN);
    int r  = i - o * (COUT * CIN);
    int co = r / CIN, ci = r - co * CIN;
    wp[i] = __float2bfloat16(w[(size_t)(co * CIN + ci) * 9 + o]);
}

// ---------------- expert weight transpose-pack: [f][P][Q] f32 -> [f][Q][P] bf16 ----------------
__global__ void __launch_bounds__(256) tpack_k(const float* __restrict__ in,
                                               __hip_bfloat16* __restrict__ out,
                                               int P, int Q, int qtiles)
{
    const int f  = blockIdx.y;
    const int pt = blockIdx.x / qtiles, qt = blockIdx.x - pt * qtiles;
    __shared__ float t[32][33];
    const float* src = in + (size_t)f * P * Q;
    __hip_bfloat16* dst = out + (size_t)f * P * Q;
    const int rr = threadIdx.x >> 5, c = threadIdx.x & 31;
    #pragma unroll
    for (int i = 0; i < 4; ++i)
        t[rr + i * 8][c] = src[(size_t)(pt * 32 + rr + i * 8) * Q + qt * 32 + c];
    __syncthreads();
    #pragma unroll
    for (int i = 0; i < 4; ++i)
        dst[(size_t)(qt * 32 + rr + i * 8) * P + pt * 32 + c] =
            __float2bfloat16(t[c][rr + i * 8]);
}

// ---------------- fw transpose: [4096][53] -> fwt[53][4096] ----------------
__global__ void __launch_bounds__(256) fwt_k(const float* __restrict__ fw, float* __restrict__ fwt)
{
    int i = blockIdx.x * 256 + threadIdx.x;
    if (i >= 53 * 4096) return;
    int o = i >> 12, k = i & 4095;
    fwt[i] = fw[(size_t)k * 53 + o];
}

// ---------------- conv1: 3->32, fp32 VALU, writes bf16 channel-last [b][64][64][32] ----------------
__global__ void __launch_bounds__(256) conv1_k(
    const float* __restrict__ x, const float* __restrict__ w,
    const float* __restrict__ bias, __hip_bfloat16* __restrict__ out)
{
    const int tile = blockIdx.x;
    const int co0  = blockIdx.y * 16;
    const int b    = blockIdx.z;
    const int tyx  = tile >> 2, txx = tile & 3;
    const int py0  = tyx * 16, px0 = txx * 16;
    const int tid  = threadIdx.x, tx = tid & 15, ty = tid >> 4;

    __shared__ float smem[3][34 * 34];
    const int y0 = py0 * 2 - 1, x0 = px0 * 2 - 1;
    for (int idx = tid; idx < 3 * 1156; idx += 256) {
        int cc = idx / 1156, rem = idx - cc * 1156;
        int iy = rem / 34, ix = rem - iy * 34;
        int gy = y0 + iy, gx = x0 + ix;
        float v = 0.f;
        if (gy >= 0 && gy < 128 && gx >= 0 && gx < 128)
            v = x[((size_t)(b * 3 + cc) * 128 + gy) * 128 + gx];
        smem[cc][rem] = v;
    }
    __syncthreads();

    float acc[16][4];
    #pragma unroll
    for (int u = 0; u < 16; ++u)
        #pragma unroll
        for (int qq = 0; qq < 4; ++qq) acc[u][qq] = 0.f;

    #pragma unroll
    for (int cc = 0; cc < 3; ++cc) {
        float r[4][4];
        #pragma unroll
        for (int d = 0; d < 4; ++d) {
            const float2 a0 = *(const float2*)&smem[cc][(2 * ty + d) * 34 + 2 * tx];
            const float2 a1 = *(const float2*)&smem[cc][(2 * ty + d) * 34 + 2 * tx + 2];
            r[d][0] = a0.x; r[d][1] = a0.y; r[d][2] = a1.x; r[d][3] = a1.y;
        }
        #pragma unroll
        for (int u = 0; u < 16; ++u) {
            const float* wp = &w[((size_t)(co0 + u) * 3 + cc) * 9];
            const float w00 = wp[0], w01 = wp[1], w02 = wp[2];
            const float w10 = wp[3], w11 = wp[4], w12 = wp[5];
            const float w20 = wp[6], w21 = wp[7], w22 = wp[8];
            #pragma unroll
            for (int sy = 0; sy < 2; ++sy)
                #pragma unroll
                for (int sx = 0; sx < 2; ++sx) {
                    float s = acc[u][sy * 2 + sx];
                    s += r[sy + 0][sx + 0] * w00 + r[sy + 0][sx + 1] * w01 + r[sy + 0][sx + 2] * w02;
                    s += r[sy + 1][sx + 0] * w10 + r[sy + 1][sx + 1] * w11 + r[sy + 1][sx + 2] * w12;
                    s += r[sy + 2][sx + 0] * w20 + r[sy + 2][sx + 1] * w21 + r[sy + 2][sx + 2] * w22;
                    acc[u][sy * 2 + sx] = s;
                }
        }
    }

    unsigned short hv[16];
    #pragma unroll
    for (int u = 0; u < 16; ++u) {
        float m = fmaxf(fmaxf(acc[u][0], acc[u][1]), fmaxf(acc[u][2], acc[u][3]));
        m = fmaxf(m + bias[co0 + u], 0.f);
        __hip_bfloat16 hb = __float2bfloat16(m);
        __builtin_memcpy(&hv[u], &hb, 2);
    }
    const int py = py0 + ty, px = px0 + tx;
    size_t obase = ((size_t)(b * 64 + py) * 64 + px) * 32 + co0;
    *(int4*)(out + obase)     = *(const int4*)&hv[0];
    *(int4*)(out + obase + 8) = *(const int4*)&hv[8];
}

// ---------------- MFMA conv3x3 + ReLU + maxpool2 (implicit GEMM, 9 shifted GEMMs) ----------------
template<int W, int CIN, int COUT, int SWZ, int OUTF>
__global__ void __launch_bounds__(256, 2) conv_mfma(
    const __hip_bfloat16* __restrict__ in,
    const __hip_bfloat16* __restrict__ wp,
    const float* __restrict__ bias,
    __hip_bfloat16* __restrict__ outb,
    float* __restrict__ outf)
{
    constexpr int XW  = W / 16;
    constexpr int AF  = 2 * XW;
    constexpr int BF  = COUT / 16;
    constexpr int CH  = CIN / 8;
    constexpr int KH  = CIN / 32;
    constexpr int PXW = W + 2;
    constexpr int UNITS  = 10 * PXW * CH;
    constexpr int STAGEB = UNITS * 16;
    constexpr int OUTLDS = OUTF ? (COUT * 68 * 4) : 0;
    constexpr int LDSB   = STAGEB > OUTLDS ? STAGEB : OUTLDS;

    __shared__ int4 ldsv[(LDSB + 15) / 16];
    char* ldsc = (char*)ldsv;

    const int rb  = blockIdx.x * 8;
    const int b   = blockIdx.z;
    const int tid = threadIdx.x;

    for (int u = tid; u < UNITS; u += 256) {
        int ch = u % CH; int pl = u / CH;
        int xx = pl % PXW; int row = pl / PXW;
        int gy = rb + row - 1, gx = xx - 1;
        int4 v = make_int4(0, 0, 0, 0);
        if (gy >= 0 && gy < W && gx >= 0 && gx < W)
            v = *(const int4*)(in + ((size_t)(b * W + gy) * W + gx) * CIN + ch * 8);
        int slot = SWZ ? (pl * CH + (ch ^ (pl & 7))) : (pl * CH + ch);
        *(int4*)(ldsc + slot * 16) = v;
    }
    __syncthreads();

    const int w = tid >> 6, lane = tid & 63, p = lane & 15, q = lane >> 4;

    f32x4 acc[AF][BF];
    #pragma unroll
    for (int m = 0; m < AF; ++m)
        #pragma unroll
        for (int n = 0; n < BF; ++n) {
            acc[m][n][0] = 0.f; acc[m][n][1] = 0.f;
            acc[m][n][2] = 0.f; acc[m][n][3] = 0.f;
        }

    float bv[BF];
    #pragma unroll
    for (int n = 0; n < BF; ++n) bv[n] = bias[n * 16 + p];

    #pragma unroll 1
    for (int o = 0; o < 9; ++o) {
        const int ky = o / 3, kx = o - 3 * (o / 3);
        #pragma unroll
        for (int h = 0; h < KH; ++h) {
            bf16x8 bfr[BF];
            #pragma unroll
            for (int n = 0; n < BF; ++n)
                bfr[n] = *(const bf16x8*)(wp + (size_t)(o * COUT + n * 16 + p) * CIN + h * 32 + q * 8);
            bf16x8 afr[AF];
            #pragma unroll
            for (int m = 0; m < AF; ++m) {
                const int mr = m / XW, mx = m % XW;
                const int pix = (2 * w + mr + ky) * PXW + mx * 16 + kx + p;
                const int ch = h * 4 + q;
                const int slot = SWZ ? (pix * CH + (ch ^ (pix & 7))) : (pix * CH + ch);
                afr[m] = *(const bf16x8*)(ldsc + slot * 16);
            }
            #pragma unroll
            for (int m = 0; m < AF; ++m)
                #pragma unroll
                for (int n = 0; n < BF; ++n)
                    acc[m][n] = __builtin_amdgcn_mfma_f32_16x16x32_bf16(afr[m], bfr[n], acc[m][n], 0, 0, 0);
        }
    }

    const int prow = (rb >> 1) + w;
    if constexpr (OUTF == 0) {
        #pragma unroll
        for (int mx = 0; mx < XW; ++mx)
            #pragma unroll
            for (int n = 0; n < BF; ++n) {
                f32x4 lo = acc[mx][n], hi = acc[XW + mx][n];
                float v0 = fmaxf(fmaxf(fmaxf(lo[0], lo[1]), fmaxf(hi[0], hi[1])) + bv[n], 0.f);
                float v1 = fmaxf(fmaxf(fmaxf(lo[2], lo[3]), fmaxf(hi[2], hi[3])) + bv[n], 0.f);
                int px = mx * 8 + q * 2;
                size_t base = ((size_t)(b * (W / 2) + prow) * (W / 2) + px) * COUT + n * 16 + p;
                outb[base]        = __float2bfloat16(v0);
                outb[base + COUT] = __float2bfloat16(v1);
            }
    } else {
        __syncthreads();
        float* fl = (float*)ldsc;
        #pragma unroll
        for (int mx = 0; mx < XW; ++mx)
            #pragma unroll
            for (int n = 0; n < BF; ++n) {
                f32x4 lo = acc[mx][n], hi = acc[XW + mx][n];
                float v0 = fmaxf(fmaxf(fmaxf(lo[0], lo[1]), fmaxf(hi[0], hi[1])) + bv[n], 0.f);
                float v1 = fmaxf(fmaxf(fmaxf(lo[2], lo[3]), fmaxf(hi[2], hi[3])) + bv[n], 0.f);
                int px = mx * 8 + q * 2;
                fl[(n * 16 + p) * 68 + w * 16 + px]     = v0;
                fl[(n * 16 + p) * 68 + w * 16 + px + 1] = v1;
            }
        __syncthreads();
        for (int i = tid; i < COUT * 16; i += 256) {
            int c = i >> 4, j4 = i & 15;
            float4 vv = *(const float4*)&fl[c * 68 + j4 * 4];
            *(float4*)(outf + (size_t)(b * COUT + c) * 256 + (rb >> 1) * 16 + j4 * 4) = vv;
        }
    }
}

// ---------------- attention gate ----------------
__global__ void __launch_bounds__(256) attention_k(
    const float* __restrict__ feat, const float* __restrict__ Wa,
    const float* __restrict__ ba, float* __restrict__ att)
{
    const int wid  = blockIdx.x * 4 + (threadIdx.x >> 6);
    const int lane = threadIdx.x & 63;
    const int b = wid >> 7, f = wid & 127;

    const float4 a  = ((const float4*)&feat[((size_t)b * NF + f) * NP])[lane];
    const float4 wv = ((const float4*)&Wa[(size_t)f * NP])[lane];
    float s = a.x * wv.x + a.y * wv.y + a.z * wv.z + a.w * wv.w;
    #pragma unroll
    for (int off = 32; off; off >>= 1) s += __shfl_down(s, off);
    if (lane == 0) att[b * NF + f] = 1.f / (1.f + expf(-(s + ba[f])));
}

// ---------------- experts via MFMA: block = (expert f, 32-row batch chunk), 32 KB LDS ----------------
// 4 waves = (row-half rh, col-half cf). X/H1: [32 rows][32 chunks16B] swizzled ch^(row&7).
// H2: [32][16] chunks, aliases X (dead after layer 1; barrier-protected).
__global__ void __launch_bounds__(256, 2) experts_mfma(
    const float* __restrict__ feat, const float* __restrict__ att,
    const __hip_bfloat16* __restrict__ w1, const float* __restrict__ eb1,
    const __hip_bfloat16* __restrict__ w2, const float* __restrict__ eb2,
    const __hip_bfloat16* __restrict__ w3, const float* __restrict__ eb3,
    float* __restrict__ z)
{
    const int f  = blockIdx.x;
    const int r0 = blockIdx.y * 32;
    const int tid = threadIdx.x;

    __shared__ char lds[32768];
    char* Xb  = lds;
    char* H1b = lds + 16384;
    char* H2b = lds;

    for (int u = tid; u < 32 * 32; u += 256) {
        int row = u >> 5, ch = u & 31;
        int b = r0 + row;
        const float* src = feat + ((size_t)b * NF + f) * NP + ch * 8;
        float g = att[b * NF + f];
        float4 v0 = *(const float4*)src;
        float4 v1 = *(const float4*)(src + 4);
        unsigned short hv[8];
        float vv[8] = {v0.x, v0.y, v0.z, v0.w, v1.x, v1.y, v1.z, v1.w};
        #pragma unroll
        for (int j = 0; j < 8; ++j) {
            __hip_bfloat16 hb = __float2bfloat16(vv[j] * g);
            __builtin_memcpy(&hv[j], &hb, 2);
        }
        int slot = row * 32 + (ch ^ (row & 7));
        *(int4*)(Xb + slot * 16) = *(const int4*)hv;
    }
    __syncthreads();

    const int wv = tid >> 6, lane = tid & 63, p = lane & 15, q = lane >> 4;
    const int rh = wv & 1, cf = wv >> 1;
    const int mrow = rh * 16;

    // ---- layer 1 ----
    f32x4 acc1[8];
    #pragma unroll
    for (int n = 0; n < 8; ++n) { acc1[n][0]=0.f; acc1[n][1]=0.f; acc1[n][2]=0.f; acc1[n][3]=0.f; }
    for (int k = 0; k < 8; ++k) {
        bf16x8 bfr[8];
        #pragma unroll
        for (int n = 0; n < 8; ++n)
            bfr[n] = *(const bf16x8*)(w1 + ((size_t)f * 256 + cf * 128 + n * 16 + p) * 256 + k * 32 + q * 8);
        int row = mrow + p, ch = k * 4 + q;
        bf16x8 afr = *(const bf16x8*)(Xb + (row * 32 + (ch ^ (row & 7))) * 16);
        #pragma unroll
        for (int n = 0; n < 8; ++n)
            acc1[n] = __builtin_amdgcn_mfma_f32_16x16x32_bf16(afr, bfr[n], acc1[n], 0, 0, 0);
    }
    #pragma unroll
    for (int n = 0; n < 8; ++n) {
        int col = cf * 128 + n * 16 + p;
        float bb = eb1[(size_t)f * 256 + col];
        #pragma unroll
        for (int reg = 0; reg < 4; ++reg) {
            float v = fmaxf(acc1[n][reg] + bb, 0.f);
            int row = mrow + q * 4 + reg;
            int slot = row * 32 + ((col >> 3) ^ (row & 7));
            *(__hip_bfloat16*)(H1b + slot * 16 + (col & 7) * 2) = __float2bfloat16(v);
        }
    }
    __syncthreads();

    // ---- layer 2 ----
    f32x4 acc2[4];
    #pragma unroll
    for (int n = 0; n < 4; ++n) { acc2[n][0]=0.f; acc2[n][1]=0.f; acc2[n][2]=0.f; acc2[n][3]=0.f; }
    for (int k = 0; k < 8; ++k) {
        bf16x8 bfr[4];
        #pragma unroll
        for (int n = 0; n < 4; ++n)
            bfr[n] = *(const bf16x8*)(w2 + ((size_t)f * 128 + cf * 64 + n * 16 + p) * 256 + k * 32 + q * 8);
        int row = mrow + p, ch = k * 4 + q;
        bf16x8 afr = *(const bf16x8*)(H1b + (row * 32 + (ch ^ (row & 7))) * 16);
        #pragma unroll
        for (int n = 0; n < 4; ++n)
            acc2[n] = __builtin_amdgcn_mfma_f32_16x16x32_bf16(afr, bfr[n], acc2[n], 0, 0, 0);
    }
    #pragma unroll
    for (int n = 0; n < 4; ++n) {
        int col = cf * 64 + n * 16 + p;
        float bb = eb2[(size_t)f * 128 + col];
        #pragma unroll
        for (int reg = 0; reg < 4; ++reg) {
            float v = fmaxf(acc2[n][reg] + bb, 0.f);
            int row = mrow + q * 4 + reg;
            int slot = row * 16 + ((col >> 3) ^ (row & 7));
            *(__hip_bfloat16*)(H2b + slot * 16 + (col & 7) * 2) = __float2bfloat16(v);
        }
    }
    __syncthreads();

    // ---- layer 3 ----
    f32x4 acc3;
    acc3[0]=0.f; acc3[1]=0.f; acc3[2]=0.f; acc3[3]=0.f;
    for (int k = 0; k < 4; ++k) {
        bf16x8 bfr = *(const bf16x8*)(w3 + ((size_t)f * 32 + cf * 16 + p) * 128 + k * 32 + q * 8);
        int row = mrow + p, ch = k * 4 + q;
        bf16x8 afr = *(const bf16x8*)(H2b + (row * 16 + (ch ^ (row & 7))) * 16);
        acc3 = __builtin_amdgcn_mfma_f32_16x16x32_bf16(afr, bfr, acc3, 0, 0, 0);
    }
    {
        float bb = eb3[(size_t)f * 32 + cf * 16 + p];
        #pragma unroll
        for (int reg = 0; reg < 4; ++reg) {
            float v = fmaxf(acc3[reg] + bb, 0.f);
            int row = r0 + mrow + q * 4 + reg;
            z[(size_t)row * 4096 + f * 32 + cf * 16 + p] = v;
        }
    }
}

// ---------------- final dense: out[b,o] = dot(z[b,:], fwt[o,:]) + fb[o] ----------------
__global__ void __launch_bounds__(256) final_k(
    const float* __restrict__ z, const float* __restrict__ fwt,
    const float* __restrict__ fb, float* __restrict__ out)
{
    const int b  = blockIdx.x;
    const int og = blockIdx.y;
    __shared__ float zs[4096];
    for (int i = threadIdx.x; i < 1024; i += 256)
        *(float4*)&zs[i * 4] = *(const float4*)&z[(size_t)b * 4096 + i * 4];
    __syncthreads();

    const int wv = threadIdx.x >> 6, lane = threadIdx.x & 63;
    const int o = og * 4 + wv;
    if (o >= 53) return;
    const float4* wr = (const float4*)&fwt[(size_t)o * 4096];
    float s = 0.f;
    #pragma unroll
    for (int it = 0; it < 16; ++it) {
        float4 zv = *(const float4*)&zs[(it * 64 + lane) * 4];
        float4 w4 = wr[it * 64 + lane];
        s += zv.x * w4.x + zv.y * w4.y + zv.z * w4.z + zv.w * w4.w;
    }
    #pragma unroll
    for (int off = 32; off; off >>= 1) s += __shfl_down(s, off);
    if (lane == 0) out[b * 53 + o] = s + fb[o];
}

extern "C" void kernel_launch(void* const* d_in, const int* in_sizes, int n_in,
                              void* d_out, int out_size, void* d_ws, size_t ws_size,
                              hipStream_t stream)
{
    const float* x   = (const float*)d_in[0];
    const float* cw1 = (const float*)d_in[1];
    const float* cb1 = (const float*)d_in[2];
    const float* cw2 = (const float*)d_in[3];
    const float* cb2 = (const float*)d_in[4];
    const float* cw3 = (const float*)d_in[5];
    const float* cb3 = (const float*)d_in[6];
    const float* Wa  = (const float*)d_in[7];
    const float* ba  = (const float*)d_in[8];
    const float* ew1 = (const float*)d_in[9];
    const float* eb1 = (const float*)d_in[10];
    const float* ew2 = (const float*)d_in[11];
    const float* eb2 = (const float*)d_in[12];
    const float* ew3 = (const float*)d_in[13];
    const float* eb3 = (const float*)d_in[14];
    const float* fw  = (const float*)d_in[15];
    const float* fb  = (const float*)d_in[16];

    // ---- workspace layout: FLOAT offsets, sizes converted bf16->float as count/2 ----
    // buffer  elems          floats      float range
    // p1b     16,777,216 b   8,388,608   [0,          8,388,608)
    // p2b      8,388,608 b   4,194,304   [8,388,608,  12,582,912)
    // feat     4,194,304 f   4,194,304   [12,582,912, 16,777,216)
    // att         16,384 f      16,384   [16,777,216, 16,793,600)
    // wp2         18,432 b       9,216   [16,793,600, 16,802,816)
    // wp3         73,728 b      36,864   [16,802,816, 16,839,680)
    // ew1b     8,388,608 b   4,194,304   [16,839,680, 21,033,984)
    // ew2b     4,194,304 b   2,097,152   [21,033,984, 23,131,136)
    // ew3b       524,288 b     262,144   [23,131,136, 23,393,280)
    // fwt        217,088 f     217,088   [23,393,280, 23,610,368)
    // z          524,288 f  -> reuses p1b region (dead after conv2)
    float* ws = (float*)d_ws;
    __hip_bfloat16* p1b  = (__hip_bfloat16*)ws;
    __hip_bfloat16* p2b  = (__hip_bfloat16*)(ws + 8388608);
    float* feat = ws + 12582912;
    float* att  = ws + 16777216;
    __hip_bfloat16* wp2  = (__hip_bfloat16*)(ws + 16793600);
    __hip_bfloat16* wp3  = (__hip_bfloat16*)(ws + 16802816);
    __hip_bfloat16* ew1b = (__hip_bfloat16*)(ws + 16839680);
    __hip_bfloat16* ew2b = (__hip_bfloat16*)(ws + 21033984);
    __hip_bfloat16* ew3b = (__hip_bfloat16*)(ws + 23131136);
    float* fwt = ws + 23393280;
    float* z   = ws;

    wpack_k<<<72, 256, 0, stream>>>(cw2, wp2, 64, 32);
    wpack_k<<<288, 256, 0, stream>>>(cw3, wp3, 128, 64);
    tpack_k<<<dim3(64, 128), 256, 0, stream>>>(ew1, ew1b, 256, 256, 8);
    tpack_k<<<dim3(32, 128), 256, 0, stream>>>(ew2, ew2b, 256, 128, 4);
    tpack_k<<<dim3(4, 128), 256, 0, stream>>>(ew3, ew3b, 128, 32, 1);
    fwt_k<<<848, 256, 0, stream>>>(fw, fwt);

    conv1_k<<<dim3(16, 2, 128), 256, 0, stream>>>(x, cw1, cb1, p1b);
    conv_mfma<64, 32, 64, 0, 0><<<dim3(8, 1, 128), 256, 0, stream>>>(p1b, wp2, cb2, p2b, nullptr);
    conv_mfma<32, 64, 128, 1, 1><<<dim3(4, 1, 128), 256, 0, stream>>>(p2b, wp3, cb3, nullptr, feat);
    attention_k<<<4096, 256, 0, stream>>>(feat, Wa, ba, att);
    experts_mfma<<<dim3(128, 4), 256, 0, stream>>>(feat, att, ew1b, eb1, ew2b, eb2, ew3b, eb3, z);
    final_k<<<dim3(128, 14), 256, 0, stream>>>(z, fwt, fb, (float*)d_out);
}

// Round 10
// 168.558 us; speedup vs baseline: 26.6613x; 1.3553x over previous
//
#include <hip/hip_runtime.h>
#include <hip/hip_bf16.h>
#include <math.h>

#define NF 128
#define NP 256

typedef __attribute__((ext_vector_type(8))) short bf16x8;
typedef __attribute__((ext_vector_type(4))) short bf16x4;
typedef __attribute__((ext_vector_type(4))) float f32x4;

// ---------------- conv weight pre-pack: [cout][cin][3][3] f32 -> [o][cout][cin] bf16 ----------------
__global__ void __launch_bounds__(256) wpack_k(const float* __restrict__ w,
                                               __hip_bfloat16* __restrict__ wp,
                                               int COUT, int CIN)
{
    int i = blockIdx.x * 256 + threadIdx.x;
    int total = 9 * COUT * CIN;
    if (i >= total) return;
    int o  = i / (COUT * CIN);
    int r  = i - o * (COUT * CIN);
    int co = r / CIN, ci = r - co * CIN;
    wp[i] = __float2bfloat16(w[(size_t)(co * CIN + ci) * 9 + o]);
}

// ---------------- conv1 weight pack: [32][3][3][3] -> wp1[2][32 co][32 k], k=(tap_local*4+ch) ----------------
// tap o = s*8 + (k>>2); zero for o>=9 or ch==3.
__global__ void __launch_bounds__(256) wpack1_k(const float* __restrict__ w,
                                                __hip_bfloat16* __restrict__ wp1)
{
    int i = blockIdx.x * 256 + threadIdx.x;
    if (i >= 2048) return;
    int s = i >> 10, co = (i >> 5) & 31, k = i & 31;
    int o = s * 8 + (k >> 2), ch = k & 3;
    float v = 0.f;
    if (o < 9 && ch < 3) v = w[(size_t)(co * 3 + ch) * 9 + o];
    wp1[i] = __float2bfloat16(v);
}

// ---------------- x transform: [128][3][128][128] f32 -> xb [128][128][128][4] bf16 (c=3 zero) ----------------
__global__ void __launch_bounds__(256) x2cl_k(const float* __restrict__ x,
                                              __hip_bfloat16* __restrict__ xb)
{
    int i = blockIdx.x * 256 + threadIdx.x;   // (b, y, x) over 128*128*128
    int b = i >> 14, rem = i & 16383;
    size_t base = ((size_t)b * 3) << 14;
    float v0 = x[base + rem];
    float v1 = x[base + 16384 + rem];
    float v2 = x[base + 32768 + rem];
    unsigned short hv[4];
    __hip_bfloat16 h0 = __float2bfloat16(v0);
    __hip_bfloat16 h1 = __float2bfloat16(v1);
    __hip_bfloat16 h2 = __float2bfloat16(v2);
    __builtin_memcpy(&hv[0], &h0, 2);
    __builtin_memcpy(&hv[1], &h1, 2);
    __builtin_memcpy(&hv[2], &h2, 2);
    hv[3] = 0;
    *(int2*)(xb + (size_t)i * 4) = *(const int2*)hv;
}

// ---------------- expert weight transpose-pack: [f][P][Q] f32 -> [f][Q][P] bf16 ----------------
__global__ void __launch_bounds__(256) tpack_k(const float* __restrict__ in,
                                               __hip_bfloat16* __restrict__ out,
                                               int P, int Q, int qtiles)
{
    const int f  = blockIdx.y;
    const int pt = blockIdx.x / qtiles, qt = blockIdx.x - pt * qtiles;
    __shared__ float t[32][33];
    const float* src = in + (size_t)f * P * Q;
    __hip_bfloat16* dst = out + (size_t)f * P * Q;
    const int rr = threadIdx.x >> 5, c = threadIdx.x & 31;
    #pragma unroll
    for (int i = 0; i < 4; ++i)
        t[rr + i * 8][c] = src[(size_t)(pt * 32 + rr + i * 8) * Q + qt * 32 + c];
    __syncthreads();
    #pragma unroll
    for (int i = 0; i < 4; ++i)
        dst[(size_t)(qt * 32 + rr + i * 8) * P + pt * 32 + c] =
            __float2bfloat16(t[c][rr + i * 8]);
}

// ---------------- fw transpose: [4096][53] -> fwt[53][4096] ----------------
__global__ void __launch_bounds__(256) fwt_k(const float* __restrict__ fw, float* __restrict__ fwt)
{
    int i = blockIdx.x * 256 + threadIdx.x;
    if (i >= 53 * 4096) return;
    int o = i >> 12, k = i & 4095;
    fwt[i] = fw[(size_t)k * 53 + o];
}

// ---------------- conv1 via MFMA: K fused over taps. 4 waves x 2 conv rows, full W=128 ----------------
// xb [128][128][128][4] bf16; out bf16 channel-last pooled [128][64][64][32].
__global__ void __launch_bounds__(256, 2) conv1_mfma(
    const __hip_bfloat16* __restrict__ xb,
    const __hip_bfloat16* __restrict__ wp1,   // [2][32][32]
    const float* __restrict__ bias,
    __hip_bfloat16* __restrict__ out)
{
    __shared__ char lds[14 * 130 * 8];        // 14 rows x 130 px x 4ch bf16
    const int rb  = blockIdx.x * 8;           // conv rows rb..rb+7
    const int b   = blockIdx.z;
    const int tid = threadIdx.x;

    for (int u = tid; u < 14 * 130; u += 256) {
        int px = u % 130, row = u / 130;
        int gy = rb + row - 1, gx = px - 1;
        int2 v = make_int2(0, 0);
        if (gy >= 0 && gy < 128 && gx >= 0 && gx < 128)
            v = *(const int2*)(xb + (((size_t)b * 128 + gy) * 128 + gx) * 4);
        *(int2*)(lds + u * 8) = v;
    }
    __syncthreads();

    const int w = tid >> 6, lane = tid & 63, p = lane & 15, q = lane >> 4;

    f32x4 acc[16][2];
    #pragma unroll
    for (int m = 0; m < 16; ++m)
        #pragma unroll
        for (int n = 0; n < 2; ++n) {
            acc[m][n][0] = 0.f; acc[m][n][1] = 0.f;
            acc[m][n][2] = 0.f; acc[m][n][3] = 0.f;
        }

    #pragma unroll
    for (int s = 0; s < 2; ++s) {
        bf16x8 bfr[2];
        #pragma unroll
        for (int n = 0; n < 2; ++n)
            bfr[n] = *(const bf16x8*)(wp1 + (size_t)(s * 32 + n * 16 + p) * 32 + q * 8);
        const int o0 = s * 8 + q * 2, o1 = o0 + 1;
        const int dy0 = o0 / 3, dx0 = o0 - 3 * dy0;     // tile row offset = o/3, col offset = o%3
        const int dy1 = o1 / 3, dx1 = o1 - 3 * dy1;
        #pragma unroll
        for (int m = 0; m < 16; ++m) {
            const int mr = m >> 3, mx = m & 7;
            const int r0 = (2 * w + mr + dy0) * 130 + mx * 16 + p + dx0;
            const int r1 = (2 * w + mr + dy1) * 130 + mx * 16 + p + dx1;
            bf16x4 lo = *(const bf16x4*)(lds + r0 * 8);
            bf16x4 hi = *(const bf16x4*)(lds + r1 * 8);
            bf16x8 afr = __builtin_shufflevector(lo, hi, 0, 1, 2, 3, 4, 5, 6, 7);
            #pragma unroll
            for (int n = 0; n < 2; ++n)
                acc[m][n] = __builtin_amdgcn_mfma_f32_16x16x32_bf16(afr, bfr[n], acc[m][n], 0, 0, 0);
        }
    }

    // pool 2x2 + bias + ReLU (same verified D mapping: co=n*16+p, conv px = mx*16 + q*4 + reg)
    const int prow = (rb >> 1) + w;
    float bv[2] = { bias[p], bias[16 + p] };
    #pragma unroll
    for (int mx = 0; mx < 8; ++mx)
        #pragma unroll
        for (int n = 0; n < 2; ++n) {
            f32x4 lo = acc[mx][n], hi = acc[8 + mx][n];
            float v0 = fmaxf(fmaxf(fmaxf(lo[0], lo[1]), fmaxf(hi[0], hi[1])) + bv[n], 0.f);
            float v1 = fmaxf(fmaxf(fmaxf(lo[2], lo[3]), fmaxf(hi[2], hi[3])) + bv[n], 0.f);
            int px = mx * 8 + q * 2;
            size_t base = ((size_t)(b * 64 + prow) * 64 + px) * 32 + n * 16 + p;
            out[base]      = __float2bfloat16(v0);
            out[base + 32] = __float2bfloat16(v1);
        }
}

// ---------------- MFMA conv3x3 + ReLU + maxpool2 (implicit GEMM, 9 shifted GEMMs) ----------------
template<int W, int CIN, int COUT, int SWZ, int OUTF>
__global__ void __launch_bounds__(256, 2) conv_mfma(
    const __hip_bfloat16* __restrict__ in,
    const __hip_bfloat16* __restrict__ wp,
    const float* __restrict__ bias,
    __hip_bfloat16* __restrict__ outb,
    float* __restrict__ outf)
{
    constexpr int XW  = W / 16;
    constexpr int AF  = 2 * XW;
    constexpr int BF  = COUT / 16;
    constexpr int CH  = CIN / 8;
    constexpr int KH  = CIN / 32;
    constexpr int PXW = W + 2;
    constexpr int UNITS  = 10 * PXW * CH;
    constexpr int STAGEB = UNITS * 16;
    constexpr int OUTLDS = OUTF ? (COUT * 68 * 4) : 0;
    constexpr int LDSB   = STAGEB > OUTLDS ? STAGEB : OUTLDS;

    __shared__ int4 ldsv[(LDSB + 15) / 16];
    char* ldsc = (char*)ldsv;

    const int rb  = blockIdx.x * 8;
    const int b   = blockIdx.z;
    const int tid = threadIdx.x;

    for (int u = tid; u < UNITS; u += 256) {
        int ch = u % CH; int pl = u / CH;
        int xx = pl % PXW; int row = pl / PXW;
        int gy = rb + row - 1, gx = xx - 1;
        int4 v = make_int4(0, 0, 0, 0);
        if (gy >= 0 && gy < W && gx >= 0 && gx < W)
            v = *(const int4*)(in + ((size_t)(b * W + gy) * W + gx) * CIN + ch * 8);
        int slot = SWZ ? (pl * CH + (ch ^ (pl & 7))) : (pl * CH + ch);
        *(int4*)(ldsc + slot * 16) = v;
    }
    __syncthreads();

    const int w = tid >> 6, lane = tid & 63, p = lane & 15, q = lane >> 4;

    f32x4 acc[AF][BF];
    #pragma unroll
    for (int m = 0; m < AF; ++m)
        #pragma unroll
        for (int n = 0; n < BF; ++n) {
            acc[m][n][0] = 0.f; acc[m][n][1] = 0.f;
            acc[m][n][2] = 0.f; acc[m][n][3] = 0.f;
        }

    float bv[BF];
    #pragma unroll
    for (int n = 0; n < BF; ++n) bv[n] = bias[n * 16 + p];

    #pragma unroll 1
    for (int o = 0; o < 9; ++o) {
        const int ky = o / 3, kx = o - 3 * (o / 3);
        #pragma unroll
        for (int h = 0; h < KH; ++h) {
            bf16x8 bfr[BF];
            #pragma unroll
            for (int n = 0; n < BF; ++n)
                bfr[n] = *(const bf16x8*)(wp + (size_t)(o * COUT + n * 16 + p) * CIN + h * 32 + q * 8);
            bf16x8 afr[AF];
            #pragma unroll
            for (int m = 0; m < AF; ++m) {
                const int mr = m / XW, mx = m % XW;
                const int pix = (2 * w + mr + ky) * PXW + mx * 16 + kx + p;
                const int ch = h * 4 + q;
                const int slot = SWZ ? (pix * CH + (ch ^ (pix & 7))) : (pix * CH + ch);
                afr[m] = *(const bf16x8*)(ldsc + slot * 16);
            }
            #pragma unroll
            for (int m = 0; m < AF; ++m)
                #pragma unroll
                for (int n = 0; n < BF; ++n)
                    acc[m][n] = __builtin_amdgcn_mfma_f32_16x16x32_bf16(afr[m], bfr[n], acc[m][n], 0, 0, 0);
        }
    }

    const int prow = (rb >> 1) + w;
    if constexpr (OUTF == 0) {
        #pragma unroll
        for (int mx = 0; mx < XW; ++mx)
            #pragma unroll
            for (int n = 0; n < BF; ++n) {
                f32x4 lo = acc[mx][n], hi = acc[XW + mx][n];
                float v0 = fmaxf(fmaxf(fmaxf(lo[0], lo[1]), fmaxf(hi[0], hi[1])) + bv[n], 0.f);
                float v1 = fmaxf(fmaxf(fmaxf(lo[2], lo[3]), fmaxf(hi[2], hi[3])) + bv[n], 0.f);
                int px = mx * 8 + q * 2;
                size_t base = ((size_t)(b * (W / 2) + prow) * (W / 2) + px) * COUT + n * 16 + p;
                outb[base]        = __float2bfloat16(v0);
                outb[base + COUT] = __float2bfloat16(v1);
            }
    } else {
        __syncthreads();
        float* fl = (float*)ldsc;
        #pragma unroll
        for (int mx = 0; mx < XW; ++mx)
            #pragma unroll
            for (int n = 0; n < BF; ++n) {
                f32x4 lo = acc[mx][n], hi = acc[XW + mx][n];
                float v0 = fmaxf(fmaxf(fmaxf(lo[0], lo[1]), fmaxf(hi[0], hi[1])) + bv[n], 0.f);
                float v1 = fmaxf(fmaxf(fmaxf(lo[2], lo[3]), fmaxf(hi[2], hi[3])) + bv[n], 0.f);
                int px = mx * 8 + q * 2;
                fl[(n * 16 + p) * 68 + w * 16 + px]     = v0;
                fl[(n * 16 + p) * 68 + w * 16 + px + 1] = v1;
            }
        __syncthreads();
        for (int i = tid; i < COUT * 16; i += 256) {
            int c = i >> 4, j4 = i & 15;
            float4 vv = *(const float4*)&fl[c * 68 + j4 * 4];
            *(float4*)(outf + (size_t)(b * COUT + c) * 256 + (rb >> 1) * 16 + j4 * 4) = vv;
        }
    }
}

// ---------------- attention gate ----------------
__global__ void __launch_bounds__(256) attention_k(
    const float* __restrict__ feat, const float* __restrict__ Wa,
    const float* __restrict__ ba, float* __restrict__ att)
{
    const int wid  = blockIdx.x * 4 + (threadIdx.x >> 6);
    const int lane = threadIdx.x & 63;
    const int b = wid >> 7, f = wid & 127;

    const float4 a  = ((const float4*)&feat[((size_t)b * NF + f) * NP])[lane];
    const float4 wv = ((const float4*)&Wa[(size_t)f * NP])[lane];
    float s = a.x * wv.x + a.y * wv.y + a.z * wv.z + a.w * wv.w;
    #pragma unroll
    for (int off = 32; off; off >>= 1) s += __shfl_down(s, off);
    if (lane == 0) att[b * NF + f] = 1.f / (1.f + expf(-(s + ba[f])));
}

// ---------------- experts via MFMA: block = (expert f, 32-row batch chunk), 32 KB LDS ----------------
__global__ void __launch_bounds__(256, 2) experts_mfma(
    const float* __restrict__ feat, const float* __restrict__ att,
    const __hip_bfloat16* __restrict__ w1, const float* __restrict__ eb1,
    const __hip_bfloat16* __restrict__ w2, const float* __restrict__ eb2,
    const __hip_bfloat16* __restrict__ w3, const float* __restrict__ eb3,
    float* __restrict__ z)
{
    const int f  = blockIdx.x;
    const int r0 = blockIdx.y * 32;
    const int tid = threadIdx.x;

    __shared__ char lds[32768];
    char* Xb  = lds;
    char* H1b = lds + 16384;
    char* H2b = lds;

    for (int u = tid; u < 32 * 32; u += 256) {
        int row = u >> 5, ch = u & 31;
        int b = r0 + row;
        const float* src = feat + ((size_t)b * NF + f) * NP + ch * 8;
        float g = att[b * NF + f];
        float4 v0 = *(const float4*)src;
        float4 v1 = *(const float4*)(src + 4);
        unsigned short hv[8];
        float vv[8] = {v0.x, v0.y, v0.z, v0.w, v1.x, v1.y, v1.z, v1.w};
        #pragma unroll
        for (int j = 0; j < 8; ++j) {
            __hip_bfloat16 hb = __float2bfloat16(vv[j] * g);
            __builtin_memcpy(&hv[j], &hb, 2);
        }
        int slot = row * 32 + (ch ^ (row & 7));
        *(int4*)(Xb + slot * 16) = *(const int4*)hv;
    }
    __syncthreads();

    const int wv = tid >> 6, lane = tid & 63, p = lane & 15, q = lane >> 4;
    const int rh = wv & 1, cf = wv >> 1;
    const int mrow = rh * 16;

    // ---- layer 1 ----
    f32x4 acc1[8];
    #pragma unroll
    for (int n = 0; n < 8; ++n) { acc1[n][0]=0.f; acc1[n][1]=0.f; acc1[n][2]=0.f; acc1[n][3]=0.f; }
    for (int k = 0; k < 8; ++k) {
        bf16x8 bfr[8];
        #pragma unroll
        for (int n = 0; n < 8; ++n)
            bfr[n] = *(const bf16x8*)(w1 + ((size_t)f * 256 + cf * 128 + n * 16 + p) * 256 + k * 32 + q * 8);
        int row = mrow + p, ch = k * 4 + q;
        bf16x8 afr = *(const bf16x8*)(Xb + (row * 32 + (ch ^ (row & 7))) * 16);
        #pragma unroll
        for (int n = 0; n < 8; ++n)
            acc1[n] = __builtin_amdgcn_mfma_f32_16x16x32_bf16(afr, bfr[n], acc1[n], 0, 0, 0);
    }
    #pragma unroll
    for (int n = 0; n < 8; ++n) {
        int col = cf * 128 + n * 16 + p;
        float bb = eb1[(size_t)f * 256 + col];
        #pragma unroll
        for (int reg = 0; reg < 4; ++reg) {
            float v = fmaxf(acc1[n][reg] + bb, 0.f);
            int row = mrow + q * 4 + reg;
            int slot = row * 32 + ((col >> 3) ^ (row & 7));
            *(__hip_bfloat16*)(H1b + slot * 16 + (col & 7) * 2) = __float2bfloat16(v);
        }
    }
    __syncthreads();

    // ---- layer 2 ----
    f32x4 acc2[4];
    #pragma unroll
    for (int n = 0; n < 4; ++n) { acc2[n][0]=0.f; acc2[n][1]=0.f; acc2[n][2]=0.f; acc2[n][3]=0.f; }
    for (int k = 0; k < 8; ++k) {
        bf16x8 bfr[4];
        #pragma unroll
        for (int n = 0; n < 4; ++n)
            bfr[n] = *(const bf16x8*)(w2 + ((size_t)f * 128 + cf * 64 + n * 16 + p) * 256 + k * 32 + q * 8);
        int row = mrow + p, ch = k * 4 + q;
        bf16x8 afr = *(const bf16x8*)(H1b + (row * 32 + (ch ^ (row & 7))) * 16);
        #pragma unroll
        for (int n = 0; n < 4; ++n)
            acc2[n] = __builtin_amdgcn_mfma_f32_16x16x32_bf16(afr, bfr[n], acc2[n], 0, 0, 0);
    }
    #pragma unroll
    for (int n = 0; n < 4; ++n) {
        int col = cf * 64 + n * 16 + p;
        float bb = eb2[(size_t)f * 128 + col];
        #pragma unroll
        for (int reg = 0; reg < 4; ++reg) {
            float v = fmaxf(acc2[n][reg] + bb, 0.f);
            int row = mrow + q * 4 + reg;
            int slot = row * 16 + ((col >> 3) ^ (row & 7));
            *(__hip_bfloat16*)(H2b + slot * 16 + (col & 7) * 2) = __float2bfloat16(v);
        }
    }
    __syncthreads();

    // ---- layer 3 ----
    f32x4 acc3;
    acc3[0]=0.f; acc3[1]=0.f; acc3[2]=0.f; acc3[3]=0.f;
    for (int k = 0; k < 4; ++k) {
        bf16x8 bfr = *(const bf16x8*)(w3 + ((size_t)f * 32 + cf * 16 + p) * 128 + k * 32 + q * 8);
        int row = mrow + p, ch = k * 4 + q;
        bf16x8 afr = *(const bf16x8*)(H2b + (row * 16 + (ch ^ (row & 7))) * 16);
        acc3 = __builtin_amdgcn_mfma_f32_16x16x32_bf16(afr, bfr, acc3, 0, 0, 0);
    }
    {
        float bb = eb3[(size_t)f * 32 + cf * 16 + p];
        #pragma unroll
        for (int reg = 0; reg < 4; ++reg) {
            float v = fmaxf(acc3[reg] + bb, 0.f);
            int row = r0 + mrow + q * 4 + reg;
            z[(size_t)row * 4096 + f * 32 + cf * 16 + p] = v;
        }
    }
}

// ---------------- final dense: out[b,o] = dot(z[b,:], fwt[o,:]) + fb[o] ----------------
__global__ void __launch_bounds__(256) final_k(
    const float* __restrict__ z, const float* __restrict__ fwt,
    const float* __restrict__ fb, float* __restrict__ out)
{
    const int b  = blockIdx.x;
    const int og = blockIdx.y;
    __shared__ float zs[4096];
    for (int i = threadIdx.x; i < 1024; i += 256)
        *(float4*)&zs[i * 4] = *(const float4*)&z[(size_t)b * 4096 + i * 4];
    __syncthreads();

    const int wv = threadIdx.x >> 6, lane = threadIdx.x & 63;
    const int o = og * 4 + wv;
    if (o >= 53) return;
    const float4* wr = (const float4*)&fwt[(size_t)o * 4096];
    float s = 0.f;
    #pragma unroll
    for (int it = 0; it < 16; ++it) {
        float4 zv = *(const float4*)&zs[(it * 64 + lane) * 4];
        float4 w4 = wr[it * 64 + lane];
        s += zv.x * w4.x + zv.y * w4.y + zv.z * w4.z + zv.w * w4.w;
    }
    #pragma unroll
    for (int off = 32; off; off >>= 1) s += __shfl_down(s, off);
    if (lane == 0) out[b * 53 + o] = s + fb[o];
}

extern "C" void kernel_launch(void* const* d_in, const int* in_sizes, int n_in,
                              void* d_out, int out_size, void* d_ws, size_t ws_size,
                              hipStream_t stream)
{
    const float* x   = (const float*)d_in[0];
    const float* cw1 = (const float*)d_in[1];
    const float* cb1 = (const float*)d_in[2];
    const float* cw2 = (const float*)d_in[3];
    const float* cb2 = (const float*)d_in[4];
    const float* cw3 = (const float*)d_in[5];
    const float* cb3 = (const float*)d_in[6];
    const float* Wa  = (const float*)d_in[7];
    const float* ba  = (const float*)d_in[8];
    const float* ew1 = (const float*)d_in[9];
    const float* eb1 = (const float*)d_in[10];
    const float* ew2 = (const float*)d_in[11];
    const float* eb2 = (const float*)d_in[12];
    const float* ew3 = (const float*)d_in[13];
    const float* eb3 = (const float*)d_in[14];
    const float* fw  = (const float*)d_in[15];
    const float* fb  = (const float*)d_in[16];

    // ---- workspace layout: FLOAT offsets (bf16 counts / 2) ----
    // p1b     16,777,216 b   [0,          8,388,608)
    // p2b      8,388,608 b   [8,388,608,  12,582,912)
    // feat     4,194,304 f   [12,582,912, 16,777,216)
    // att         16,384 f   [16,777,216, 16,793,600)
    // wp2         18,432 b   [16,793,600, 16,802,816)
    // wp3         73,728 b   [16,802,816, 16,839,680)
    // ew1b     8,388,608 b   [16,839,680, 21,033,984)
    // ew2b     4,194,304 b   [21,033,984, 23,131,136)
    // ew3b       524,288 b   [23,131,136, 23,393,280)
    // fwt        217,088 f   [23,393,280, 23,610,368)
    // wp1b         2,048 b   [23,610,368, 23,611,392)
    // xb       8,388,608 b   [23,611,392, 27,805,696)   (111.2 MB total)
    // z          524,288 f   -> reuses p1b region (dead after conv2)
    float* ws = (float*)d_ws;
    __hip_bfloat16* p1b  = (__hip_bfloat16*)ws;
    __hip_bfloat16* p2b  = (__hip_bfloat16*)(ws + 8388608);
    float* feat = ws + 12582912;
    float* att  = ws + 16777216;
    __hip_bfloat16* wp2  = (__hip_bfloat16*)(ws + 16793600);
    __hip_bfloat16* wp3  = (__hip_bfloat16*)(ws + 16802816);
    __hip_bfloat16* ew1b = (__hip_bfloat16*)(ws + 16839680);
    __hip_bfloat16* ew2b = (__hip_bfloat16*)(ws + 21033984);
    __hip_bfloat16* ew3b = (__hip_bfloat16*)(ws + 23131136);
    float* fwt = ws + 23393280;
    __hip_bfloat16* wp1b = (__hip_bfloat16*)(ws + 23610368);
    __hip_bfloat16* xb   = (__hip_bfloat16*)(ws + 23611392);
    float* z   = ws;

    wpack1_k<<<8, 256, 0, stream>>>(cw1, wp1b);
    wpack_k<<<72, 256, 0, stream>>>(cw2, wp2, 64, 32);
    wpack_k<<<288, 256, 0, stream>>>(cw3, wp3, 128, 64);
    tpack_k<<<dim3(64, 128), 256, 0, stream>>>(ew1, ew1b, 256, 256, 8);
    tpack_k<<<dim3(32, 128), 256, 0, stream>>>(ew2, ew2b, 256, 128, 4);
    tpack_k<<<dim3(4, 128), 256, 0, stream>>>(ew3, ew3b, 128, 32, 1);
    fwt_k<<<848, 256, 0, stream>>>(fw, fwt);

    x2cl_k<<<8192, 256, 0, stream>>>(x, xb);
    conv1_mfma<<<dim3(16, 1, 128), 256, 0, stream>>>(xb, wp1b, cb1, p1b);
    conv_mfma<64, 32, 64, 0, 0><<<dim3(8, 1, 128), 256, 0, stream>>>(p1b, wp2, cb2, p2b, nullptr);
    conv_mfma<32, 64, 128, 1, 1><<<dim3(4, 1, 128), 256, 0, stream>>>(p2b, wp3, cb3, nullptr, feat);
    attention_k<<<4096, 256, 0, stream>>>(feat, Wa, ba, att);
    experts_mfma<<<dim3(128, 4), 256, 0, stream>>>(feat, att, ew1b, eb1, ew2b, eb2, ew3b, eb3, z);
    final_k<<<dim3(128, 14), 256, 0, stream>>>(z, fwt, fb, (float*)d_out);
}